// Round 1
// 1683.503 us; speedup vs baseline: 1.0871x; 1.0871x over previous
//
#include <hip/hip_runtime.h>
#include <hip/hip_bf16.h>

// Problem constants
#define T_TOKENS 8192   // SEQ*BS
#define H_DIM 2048
#define I_DIM 4096
#define E_EXP 8
#define PAD_ROWS 9216   // 8192 + 8*128 worst-case padded segment total

typedef __bf16 bf16x8 __attribute__((ext_vector_type(8)));
typedef float floatx4 __attribute__((ext_vector_type(4)));
typedef unsigned short ushort8 __attribute__((ext_vector_type(8)));

__device__ __forceinline__ unsigned short f2bf(float f) {
  // round-to-nearest-even f32 -> bf16 (inputs are finite; no NaN handling needed)
  union { float f; unsigned int i; } c; c.f = f;
  unsigned int x = c.i;
  unsigned int r = x + 0x7fffu + ((x >> 16) & 1u);
  return (unsigned short)(r >> 16);
}

__device__ __forceinline__ float bf2float(unsigned short u) {
  union { unsigned int i; float f; } c; c.i = ((unsigned int)u) << 16;
  return c.f;
}

// async global->LDS, 16B per lane. LDS dest = wave-uniform base + lane*16.
// Global source is PER-LANE -> swizzled layouts done by pre-swizzling the
// source address while keeping LDS linear (guide §5 / m173).
__device__ __forceinline__ void gload_lds16(const void* g, void* l) {
  __builtin_amdgcn_global_load_lds(
      (const __attribute__((address_space(1))) void*)g,
      (__attribute__((address_space(3))) void*)l, 16, 0, 0);
}

// ---------------------------------------------------------------------------
// K0: zero header + convert hidden_states fp32 -> bf16 (x_bf)
// ---------------------------------------------------------------------------
__global__ __launch_bounds__(256) void xcvt_kernel(const float* __restrict__ x,
                                                   unsigned short* __restrict__ xb,
                                                   int* __restrict__ hdr) {
  if (blockIdx.x == 0 && threadIdx.x < 32) hdr[threadIdx.x] = 0;
  int i = (blockIdx.x * 256 + threadIdx.x) * 4;
  floatx4 v = *(const floatx4*)(x + i);
  unsigned short o0 = f2bf(v[0]), o1 = f2bf(v[1]), o2 = f2bf(v[2]), o3 = f2bf(v[3]);
  ushort4 o; o.x = o0; o.y = o1; o.z = o2; o.w = o3;
  *(ushort4*)(xb + i) = o;
}

// ---------------------------------------------------------------------------
// K1: router logits + argmax (one wave per token), histogram via atomics
// hdr layout (ints): cnt[8] @0, cursor[8] @8, seg[8] @16
// ---------------------------------------------------------------------------
__global__ __launch_bounds__(256) void router_kernel(const float* __restrict__ x,
                                                     const float* __restrict__ rw,
                                                     int* __restrict__ idx,
                                                     int* __restrict__ hdr) {
  int lane = threadIdx.x & 63;
  int t = blockIdx.x * 4 + (threadIdx.x >> 6);
  const float* xr = x + (size_t)t * H_DIM;
  float acc[8];
#pragma unroll
  for (int e = 0; e < 8; ++e) acc[e] = 0.f;
  for (int i = lane; i < H_DIM; i += 64) {
    float h = xr[i];
    floatx4 r0 = *(const floatx4*)(rw + i * 8);
    floatx4 r1 = *(const floatx4*)(rw + i * 8 + 4);
#pragma unroll
    for (int e = 0; e < 4; ++e) { acc[e] += h * r0[e]; acc[e + 4] += h * r1[e]; }
  }
#pragma unroll
  for (int off = 32; off > 0; off >>= 1)
#pragma unroll
    for (int e = 0; e < 8; ++e) acc[e] += __shfl_xor(acc[e], off, 64);
  if (lane == 0) {
    int best = 0; float bv = acc[0];
#pragma unroll
    for (int e = 1; e < 8; ++e) if (acc[e] > bv) { bv = acc[e]; best = e; }
    idx[t] = best;
    atomicAdd(&hdr[best], 1);
  }
}

// ---------------------------------------------------------------------------
// K2: segment bases (128-aligned) + rows[] sentinel init
// ---------------------------------------------------------------------------
__global__ __launch_bounds__(256) void setup_kernel(int* __restrict__ hdr,
                                                    int* __restrict__ rows) {
  if (threadIdx.x == 0) {
    int b = 0;
    for (int e = 0; e < 8; ++e) {
      hdr[16 + e] = b;
      b += ((hdr[e] + 127) >> 7) << 7;
    }
  }
  for (int i = threadIdx.x; i < PAD_ROWS; i += 256) rows[i] = -1;
}

// ---------------------------------------------------------------------------
// K3: scatter token ids into per-expert segments
// ---------------------------------------------------------------------------
__global__ __launch_bounds__(256) void scatter_kernel(const int* __restrict__ idx,
                                                      int* __restrict__ hdr,
                                                      int* __restrict__ rows) {
  int t = blockIdx.x * 256 + threadIdx.x;
  int e = idx[t];
  int p = atomicAdd(&hdr[8 + e], 1);
  rows[hdr[16 + e] + p] = t;
}

// ---------------------------------------------------------------------------
// K4: weight prepass — fp32 W[e][K][N] -> bf16 Wt[e][N][K] (convert+transpose)
// 64x64 tile per block via LDS. Slot-swizzled tile (8 slots of 8 bf16/row,
// physslot = slot ^ (k&7)) so both phases are aggregate-conflict-free.
// Phase1: thread (k=tid>>2, n0=(tid&3)*16) reads 64B/row coalesced, writes 2
// swizzled 16B slots. Phase2: lane n=tid&63 gathers 16 bf16 along k (2-way,
// free per m136) and stores 32B contiguous at the transposed row.
// ---------------------------------------------------------------------------
template <int K, int N>
__global__ __launch_bounds__(256) void wtrans_kernel(const float* __restrict__ W,
                                                     unsigned short* __restrict__ Wt) {
  __shared__ unsigned short tile[64 * 64];
  const int e = blockIdx.z;
  const int bn = blockIdx.x * 64;
  const int bk = blockIdx.y * 64;
  const float* Wp = W + (size_t)e * K * N;
  unsigned short* Wtp = Wt + (size_t)e * N * K;
  const int tid = threadIdx.x;

  {
    const int k = tid >> 2;
    const int n0 = (tid & 3) * 16;
    const float* src = Wp + (size_t)(bk + k) * N + bn + n0;
    floatx4 v0 = *(const floatx4*)(src);
    floatx4 v1 = *(const floatx4*)(src + 4);
    floatx4 v2 = *(const floatx4*)(src + 8);
    floatx4 v3 = *(const floatx4*)(src + 12);
    ushort8 p0, p1;
#pragma unroll
    for (int i = 0; i < 4; ++i) {
      p0[i] = f2bf(v0[i]); p0[4 + i] = f2bf(v1[i]);
      p1[i] = f2bf(v2[i]); p1[4 + i] = f2bf(v3[i]);
    }
    const int s0 = (tid & 3) * 2;
    *(ushort8*)(tile + k * 64 + ((s0 ^ (k & 7)) << 3)) = p0;
    *(ushort8*)(tile + k * 64 + (((s0 + 1) ^ (k & 7)) << 3)) = p1;
  }
  __syncthreads();
  {
    const int n = tid & 63;
    const int wv = tid >> 6;
    const int nhi = n >> 3, nlo = n & 7;
    ushort8 o0, o1;
#pragma unroll
    for (int i = 0; i < 8; ++i) {
      const int k0 = wv * 16 + i;
      const int k1 = k0 + 8;
      o0[i] = tile[k0 * 64 + (((nhi ^ (k0 & 7)) << 3) | nlo)];
      o1[i] = tile[k1 * 64 + (((nhi ^ (k1 & 7)) << 3) | nlo)];
    }
    unsigned short* dst = Wtp + (size_t)(bn + n) * K + bk + wv * 16;
    *(ushort8*)(dst) = o0;
    *(ushort8*)(dst + 8) = o1;
  }
}

// ---------------------------------------------------------------------------
// Grouped GEMM, m97 structure. 128x128 tile, BK=64, 256 threads = 4 waves,
// each wave 64x64 via 4x4 frags of mfma_f32_16x16x32_bf16.
// A: bf16 [rows][K] (k-contiguous), gathered via rows[] when GATHER
// (padding rows redirected to row 0; their outputs are dropped at MODE 2).
// Bt: bf16 [E][NTOT][K] pre-transposed (k-contiguous).
// Staging: global_load_lds width=16, LDS XOR-swizzled via pre-swizzled
// per-lane SOURCE (linear LDS dest) + matching swizzle on ds_read_b128:
//   phys16Bslot(row, slot) = slot ^ (row & 7)
// MODE 0: write gtmp bf16 (gate). MODE 1: silu(gtmp)*acc -> inter bf16 (up).
// MODE 2: scatter fp32 rows to outp by token (down).
// ---------------------------------------------------------------------------
template <int K, int NTOT, bool GATHER, int MODE>
__global__ __launch_bounds__(256) void moe_gemm(const unsigned short* __restrict__ A,
                                                const unsigned short* __restrict__ Bt,
                                                const int* __restrict__ hdr,
                                                const int* __restrict__ rows,
                                                unsigned short* __restrict__ gtmp,
                                                unsigned short* __restrict__ inter,
                                                float* __restrict__ outp) {
  const int e = blockIdx.z;
  const int cnt = hdr[e];
  if ((int)blockIdx.y * 128 >= cnt) return;  // uniform early exit
  const int seg = hdr[16 + e];

  const int tid = threadIdx.x;
  const int lane = tid & 63;
  const int wv = tid >> 6;
  const int wm = (wv & 1) * 64;
  const int wn = (wv >> 1) * 64;
  const int q = lane >> 4;
  const int l15 = lane & 15;

  __shared__ unsigned short sA[128 * 64];  // [m][64k] bf16, slot-swizzled
  __shared__ unsigned short sB[128 * 64];  // [n][64k] bf16, slot-swizzled

  // Staging geometry: chunk j covers rows j*32 + wv*8 .. +7 (wave-uniform LDS
  // base); lane covers row +(lane>>3), 16B slot (lane&7). Source k-offset is
  // the swizzled slot so the linear DMA write lands the swizzled layout.
  const int lr = lane >> 3;                 // row within 8-row chunk == row&7
  const int colsw = (lane & 7) ^ lr;        // pre-swizzled 8-elem slot index
  const unsigned short* aptr[4];
  const unsigned short* bptr[4];
  const unsigned short* Be = Bt + (size_t)e * NTOT * K;
#pragma unroll
  for (int j = 0; j < 4; ++j) {
    const int R = j * 32 + wv * 8 + lr;
    int ar;
    if (GATHER) {
      ar = rows[seg + blockIdx.y * 128 + R];
      if (ar < 0) ar = 0;  // padding rows: junk compute, dropped at scatter
    } else {
      ar = seg + blockIdx.y * 128 + R;
    }
    aptr[j] = A + (size_t)ar * K + colsw * 8;
    bptr[j] = Be + (size_t)(blockIdx.x * 128 + R) * K + colsw * 8;
  }

  floatx4 acc[4][4];
#pragma unroll
  for (int a = 0; a < 4; ++a)
#pragma unroll
    for (int b = 0; b < 4; ++b) acc[a][b] = (floatx4){0.f, 0.f, 0.f, 0.f};

  for (int kt = 0; kt < K; kt += 64) {
    // ---- stage A and B tiles via async DMA (no VGPR roundtrip, no VALU) ----
#pragma unroll
    for (int j = 0; j < 4; ++j) {
      gload_lds16(aptr[j] + kt, sA + (j * 32 + wv * 8) * 64);
      gload_lds16(bptr[j] + kt, sB + (j * 32 + wv * 8) * 64);
    }
    __syncthreads();  // compiler inserts vmcnt(0): DMA complete for all waves
    // ---- compute: 2 k-steps of 32 ----
#pragma unroll
    for (int ks = 0; ks < 64; ks += 32) {
      const int sbase = ks >> 3;  // 0 or 4 (8-elem slot units)
      bf16x8 af[4], bfr[4];
#pragma unroll
      for (int fm = 0; fm < 4; ++fm) {
        const int ra = wm + fm * 16 + l15;
        af[fm] = __builtin_bit_cast(bf16x8,
            *(const ushort8*)(sA + ra * 64 + (((q + sbase) ^ (ra & 7)) << 3)));
      }
#pragma unroll
      for (int fn = 0; fn < 4; ++fn) {
        const int rb = wn + fn * 16 + l15;
        bfr[fn] = __builtin_bit_cast(bf16x8,
            *(const ushort8*)(sB + rb * 64 + (((q + sbase) ^ (rb & 7)) << 3)));
      }
#pragma unroll
      for (int fm = 0; fm < 4; ++fm)
#pragma unroll
        for (int fn = 0; fn < 4; ++fn)
          acc[fm][fn] = __builtin_amdgcn_mfma_f32_16x16x32_bf16(af[fm], bfr[fn],
                                                                acc[fm][fn], 0, 0, 0);
    }
    __syncthreads();
  }

  // ---- epilogue: C/D layout col=lane&15, row=(lane>>4)*4+reg ----
#pragma unroll
  for (int fm = 0; fm < 4; ++fm)
#pragma unroll
    for (int fn = 0; fn < 4; ++fn)
#pragma unroll
      for (int rr = 0; rr < 4; ++rr) {
        const int row = wm + fm * 16 + q * 4 + rr;
        const int col = wn + fn * 16 + l15;
        const int gm = blockIdx.y * 128 + row;
        const int gn = blockIdx.x * 128 + col;
        const float v = acc[fm][fn][rr];
        const size_t pos = (size_t)(seg + gm);
        if (MODE == 0) {
          gtmp[pos * NTOT + gn] = f2bf(v);
        } else if (MODE == 1) {
          const float g = bf2float(gtmp[pos * NTOT + gn]);
          const float s = g / (1.f + __expf(-g));  // silu
          inter[pos * NTOT + gn] = f2bf(s * v);
        } else {
          const int tok = rows[pos];
          if (tok >= 0) outp[(size_t)tok * NTOT + gn] = v;
        }
      }
}

// ---------------------------------------------------------------------------
// host launcher
// ---------------------------------------------------------------------------
extern "C" void kernel_launch(void* const* d_in, const int* in_sizes, int n_in,
                              void* d_out, int out_size, void* d_ws, size_t ws_size,
                              hipStream_t stream) {
  const float* hidden   = (const float*)d_in[0];
  const float* router_w = (const float*)d_in[1];
  const float* gate_w   = (const float*)d_in[2];
  const float* up_w     = (const float*)d_in[3];
  const float* down_w   = (const float*)d_in[4];
  float* out = (float*)d_out;

  char* ws = (char*)d_ws;
  // ws layout (bytes), with time-aliasing (stream-serial kernels):
  //   hdr   @ 0         : 32 ints
  //   idx   @ 1024      : 8192 ints            (32768 B)
  //   rows  @ 33792     : 9216 ints            (36864 B)
  //   x_bf  @ 70656     : 8192*2048 bf16       (33554432 B)
  //   g_tmp @ 33625088  : 9216*4096 bf16       (75497472 B)
  //   W1    @ 109122560 : 134217728 B  = gate_bt [8][4096][2048] bf16,
  //                       then (after gate GEMM) inter [9216][4096] bf16
  //   W2    @ 243340288 : 134217728 B  = up_bt [8][4096][2048] bf16,
  //                       then (after up GEMM) down_bt [8][2048][4096] bf16
  //   total = 377558016 B (~378 MB)
  int* hdr  = (int*)ws;
  int* idx  = (int*)(ws + 1024);
  int* rows = (int*)(ws + 33792);
  unsigned short* x_bf  = (unsigned short*)(ws + 70656);
  unsigned short* g_tmp = (unsigned short*)(ws + 33625088);
  unsigned short* W1    = (unsigned short*)(ws + 109122560);
  unsigned short* W2    = (unsigned short*)(ws + 243340288);
  unsigned short* inter = W1;  // alias: gate_bt dead after gate GEMM
  unsigned short* downt = W2;  // alias: up_bt dead after up GEMM

  xcvt_kernel<<<T_TOKENS * H_DIM / 1024, 256, 0, stream>>>(hidden, x_bf, hdr);
  router_kernel<<<T_TOKENS / 4, 256, 0, stream>>>(hidden, router_w, idx, hdr);
  setup_kernel<<<1, 256, 0, stream>>>(hdr, rows);
  scatter_kernel<<<T_TOKENS / 256, 256, 0, stream>>>(idx, hdr, rows);

  // weight prepasses (gate, up) — fp32 [K][N] -> bf16 [N][K]
  wtrans_kernel<H_DIM, I_DIM><<<dim3(I_DIM / 64, H_DIM / 64, E_EXP), 256, 0, stream>>>(gate_w, W1);
  wtrans_kernel<H_DIM, I_DIM><<<dim3(I_DIM / 64, H_DIM / 64, E_EXP), 256, 0, stream>>>(up_w, W2);

  // gate GEMM: writes g_tmp
  moe_gemm<H_DIM, I_DIM, true, 0><<<dim3(I_DIM / 128, 64, E_EXP), 256, 0, stream>>>(
      x_bf, W1, hdr, rows, g_tmp, nullptr, nullptr);
  // up GEMM: silu(g_tmp)*up -> inter (aliases W1; gate_bt no longer needed)
  moe_gemm<H_DIM, I_DIM, true, 1><<<dim3(I_DIM / 128, 64, E_EXP), 256, 0, stream>>>(
      x_bf, W2, hdr, rows, g_tmp, inter, nullptr);

  // down prepass into W2 (up_bt dead), then down GEMM scatters to out
  wtrans_kernel<I_DIM, H_DIM><<<dim3(H_DIM / 64, I_DIM / 64, E_EXP), 256, 0, stream>>>(down_w, downt);
  moe_gemm<I_DIM, H_DIM, false, 2><<<dim3(H_DIM / 128, 64, E_EXP), 256, 0, stream>>>(
      inter, downt, hdr, rows, nullptr, nullptr, out);
}

// Round 2
// 1549.391 us; speedup vs baseline: 1.1812x; 1.0866x over previous
//
#include <hip/hip_runtime.h>
#include <hip/hip_bf16.h>

// Problem constants
#define T_TOKENS 8192   // SEQ*BS
#define H_DIM 2048
#define I_DIM 4096
#define E_EXP 8
#define PAD_ROWS 9216   // 8192 + 8*128 worst-case padded segment total

typedef __bf16 bf16x8 __attribute__((ext_vector_type(8)));
typedef float floatx4 __attribute__((ext_vector_type(4)));
typedef unsigned short ushort8 __attribute__((ext_vector_type(8)));

__device__ __forceinline__ unsigned short f2bf(float f) {
  // round-to-nearest-even f32 -> bf16 (inputs are finite; no NaN handling needed)
  union { float f; unsigned int i; } c; c.f = f;
  unsigned int x = c.i;
  unsigned int r = x + 0x7fffu + ((x >> 16) & 1u);
  return (unsigned short)(r >> 16);
}

__device__ __forceinline__ float bf2float(unsigned short u) {
  union { unsigned int i; float f; } c; c.i = ((unsigned int)u) << 16;
  return c.f;
}

// async global->LDS, 16B per lane. LDS dest = wave-uniform base + lane*16.
// Global source is PER-LANE -> swizzled layouts done by pre-swizzling the
// source address while keeping LDS linear (guide §5 / m173).
__device__ __forceinline__ void gload_lds16(const void* g, void* l) {
  __builtin_amdgcn_global_load_lds(
      (const __attribute__((address_space(1))) void*)g,
      (__attribute__((address_space(3))) void*)l, 16, 0, 0);
}

// ---------------------------------------------------------------------------
// K0: zero header + convert hidden_states fp32 -> bf16 (x_bf)
// ---------------------------------------------------------------------------
__global__ __launch_bounds__(256) void xcvt_kernel(const float* __restrict__ x,
                                                   unsigned short* __restrict__ xb,
                                                   int* __restrict__ hdr) {
  if (blockIdx.x == 0 && threadIdx.x < 32) hdr[threadIdx.x] = 0;
  int i = (blockIdx.x * 256 + threadIdx.x) * 4;
  floatx4 v = *(const floatx4*)(x + i);
  unsigned short o0 = f2bf(v[0]), o1 = f2bf(v[1]), o2 = f2bf(v[2]), o3 = f2bf(v[3]);
  ushort4 o; o.x = o0; o.y = o1; o.z = o2; o.w = o3;
  *(ushort4*)(xb + i) = o;
}

// ---------------------------------------------------------------------------
// K1: router logits + argmax (one wave per token), histogram via atomics
// hdr layout (ints): cnt[8] @0, cursor[8] @8, seg[8] @16
// ---------------------------------------------------------------------------
__global__ __launch_bounds__(256) void router_kernel(const float* __restrict__ x,
                                                     const float* __restrict__ rw,
                                                     int* __restrict__ idx,
                                                     int* __restrict__ hdr) {
  int lane = threadIdx.x & 63;
  int t = blockIdx.x * 4 + (threadIdx.x >> 6);
  const float* xr = x + (size_t)t * H_DIM;
  float acc[8];
#pragma unroll
  for (int e = 0; e < 8; ++e) acc[e] = 0.f;
  for (int i = lane; i < H_DIM; i += 64) {
    float h = xr[i];
    floatx4 r0 = *(const floatx4*)(rw + i * 8);
    floatx4 r1 = *(const floatx4*)(rw + i * 8 + 4);
#pragma unroll
    for (int e = 0; e < 4; ++e) { acc[e] += h * r0[e]; acc[e + 4] += h * r1[e]; }
  }
#pragma unroll
  for (int off = 32; off > 0; off >>= 1)
#pragma unroll
    for (int e = 0; e < 8; ++e) acc[e] += __shfl_xor(acc[e], off, 64);
  if (lane == 0) {
    int best = 0; float bv = acc[0];
#pragma unroll
    for (int e = 1; e < 8; ++e) if (acc[e] > bv) { bv = acc[e]; best = e; }
    idx[t] = best;
    atomicAdd(&hdr[best], 1);
  }
}

// ---------------------------------------------------------------------------
// K2: segment bases (128-aligned) + rows[] sentinel init
// ---------------------------------------------------------------------------
__global__ __launch_bounds__(256) void setup_kernel(int* __restrict__ hdr,
                                                    int* __restrict__ rows) {
  if (threadIdx.x == 0) {
    int b = 0;
    for (int e = 0; e < 8; ++e) {
      hdr[16 + e] = b;
      b += ((hdr[e] + 127) >> 7) << 7;
    }
  }
  for (int i = threadIdx.x; i < PAD_ROWS; i += 256) rows[i] = -1;
}

// ---------------------------------------------------------------------------
// K3: scatter token ids into per-expert segments
// ---------------------------------------------------------------------------
__global__ __launch_bounds__(256) void scatter_kernel(const int* __restrict__ idx,
                                                      int* __restrict__ hdr,
                                                      int* __restrict__ rows) {
  int t = blockIdx.x * 256 + threadIdx.x;
  int e = idx[t];
  int p = atomicAdd(&hdr[8 + e], 1);
  rows[hdr[16 + e] + p] = t;
}

// ---------------------------------------------------------------------------
// K4: weight prepass — fp32 W[e][K][N] -> bf16 Wt[e][N][K] (convert+transpose)
// Pure-register transpose, no LDS (previous LDS version was ds_read_u16
// issue-bound at ~4x the BW roofline). Each thread owns an 8(k) x 8(n) fp32
// sub-block: 16 coalesced float4 loads (32B/lane/row), static-index register
// transpose (rule #20: all indices compile-time), 8x 16B stores along the
// transposed rows. The 8 threads sharing an output 128B line (k_sub 0..7)
// are in the same block so L2 write-combines full lines.
// Block tile: 64(k) x 256(n); grid (N/256, K/64, E).
// ---------------------------------------------------------------------------
template <int K, int N>
__global__ __launch_bounds__(256) void wtrans_kernel(const float* __restrict__ W,
                                                     unsigned short* __restrict__ Wt) {
  const int e = blockIdx.z;
  const int bn = blockIdx.x * 256;
  const int bk = blockIdx.y * 64;
  const float* Wp = W + (size_t)e * K * N;
  unsigned short* Wtp = Wt + (size_t)e * N * K;
  const int tid = threadIdx.x;
  const int n0 = (tid & 31) * 8;
  const int k0 = (tid >> 5) * 8;

  const float* src = Wp + (size_t)(bk + k0) * N + bn + n0;
  floatx4 a[8][2];
#pragma unroll
  for (int kk = 0; kk < 8; ++kk) {
    a[kk][0] = *(const floatx4*)(src + (size_t)kk * N);
    a[kk][1] = *(const floatx4*)(src + (size_t)kk * N + 4);
  }
  unsigned short* dst = Wtp + (size_t)(bn + n0) * K + bk + k0;
#pragma unroll
  for (int nn = 0; nn < 8; ++nn) {
    ushort8 o;
#pragma unroll
    for (int kk = 0; kk < 8; ++kk) o[kk] = f2bf(a[kk][nn >> 2][nn & 3]);
    *(ushort8*)(dst + (size_t)nn * K) = o;
  }
}

// ---------------------------------------------------------------------------
// K5: fused gate+up grouped GEMM. 128x128 tile, BK=64, 256 threads = 4 waves,
// each wave 64x64 via 4x4 frags of mfma_f32_16x16x32_bf16, TWO accumulator
// sets (gate, up). A staged once per k-tile, both B tiles staged -> 32 MFMA
// per barrier pair (2x the per-barrier MFMA of the unfused version, halving
// the relative vmcnt(0)+barrier drain). Epilogue: inter = silu(g_f32) * u,
// no g_tmp round-trip.
// Staging: global_load_lds width=16, XOR-swizzled via pre-swizzled per-lane
// SOURCE (linear LDS dest) + matching swizzle on ds_read_b128:
//   phys16Bslot(row, slot) = slot ^ (row & 7)
// ---------------------------------------------------------------------------
__global__ __launch_bounds__(256, 2) void moe_gemm_gu(
    const unsigned short* __restrict__ A,
    const unsigned short* __restrict__ Bg,
    const unsigned short* __restrict__ Bu,
    const int* __restrict__ hdr,
    const int* __restrict__ rows,
    unsigned short* __restrict__ inter) {
  const int e = blockIdx.z;
  const int cnt = hdr[e];
  if ((int)blockIdx.y * 128 >= cnt) return;  // uniform early exit
  const int seg = hdr[16 + e];

  const int tid = threadIdx.x;
  const int lane = tid & 63;
  const int wv = tid >> 6;
  const int wm = (wv & 1) * 64;
  const int wn = (wv >> 1) * 64;
  const int q = lane >> 4;
  const int l15 = lane & 15;

  __shared__ unsigned short sA[128 * 64];   // [m][64k] bf16, slot-swizzled
  __shared__ unsigned short sBg[128 * 64];  // [n][64k] gate
  __shared__ unsigned short sBu[128 * 64];  // [n][64k] up

  const int lr = lane >> 3;            // row within 8-row chunk == row&7
  const int colsw = (lane & 7) ^ lr;   // pre-swizzled 8-elem slot index
  const unsigned short* aptr[4];
  const unsigned short* bgptr[4];
  const unsigned short* buptr[4];
  const unsigned short* BgE = Bg + (size_t)e * I_DIM * H_DIM;  // [N][K]
  const unsigned short* BuE = Bu + (size_t)e * I_DIM * H_DIM;
#pragma unroll
  for (int j = 0; j < 4; ++j) {
    const int R = j * 32 + wv * 8 + lr;
    int ar = rows[seg + blockIdx.y * 128 + R];
    if (ar < 0) ar = 0;  // padding rows: junk compute, dropped downstream
    aptr[j] = A + (size_t)ar * H_DIM + colsw * 8;
    bgptr[j] = BgE + (size_t)(blockIdx.x * 128 + R) * H_DIM + colsw * 8;
    buptr[j] = BuE + (size_t)(blockIdx.x * 128 + R) * H_DIM + colsw * 8;
  }

  floatx4 accg[4][4], accu[4][4];
#pragma unroll
  for (int a = 0; a < 4; ++a)
#pragma unroll
    for (int b = 0; b < 4; ++b) {
      accg[a][b] = (floatx4){0.f, 0.f, 0.f, 0.f};
      accu[a][b] = (floatx4){0.f, 0.f, 0.f, 0.f};
    }

  for (int kt = 0; kt < H_DIM; kt += 64) {
#pragma unroll
    for (int j = 0; j < 4; ++j) {
      gload_lds16(aptr[j] + kt, sA + (j * 32 + wv * 8) * 64);
      gload_lds16(bgptr[j] + kt, sBg + (j * 32 + wv * 8) * 64);
      gload_lds16(buptr[j] + kt, sBu + (j * 32 + wv * 8) * 64);
    }
    __syncthreads();  // compiler inserts vmcnt(0): DMA complete for all waves
#pragma unroll
    for (int ks = 0; ks < 64; ks += 32) {
      const int sbase = ks >> 3;  // 0 or 4 (8-elem slot units)
      bf16x8 af[4], bfr[4];
#pragma unroll
      for (int fm = 0; fm < 4; ++fm) {
        const int ra = wm + fm * 16 + l15;
        af[fm] = __builtin_bit_cast(bf16x8,
            *(const ushort8*)(sA + ra * 64 + (((q + sbase) ^ (ra & 7)) << 3)));
      }
#pragma unroll
      for (int fn = 0; fn < 4; ++fn) {
        const int rb = wn + fn * 16 + l15;
        bfr[fn] = __builtin_bit_cast(bf16x8,
            *(const ushort8*)(sBg + rb * 64 + (((q + sbase) ^ (rb & 7)) << 3)));
      }
#pragma unroll
      for (int fm = 0; fm < 4; ++fm)
#pragma unroll
        for (int fn = 0; fn < 4; ++fn)
          accg[fm][fn] = __builtin_amdgcn_mfma_f32_16x16x32_bf16(af[fm], bfr[fn],
                                                                 accg[fm][fn], 0, 0, 0);
#pragma unroll
      for (int fn = 0; fn < 4; ++fn) {
        const int rb = wn + fn * 16 + l15;
        bfr[fn] = __builtin_bit_cast(bf16x8,
            *(const ushort8*)(sBu + rb * 64 + (((q + sbase) ^ (rb & 7)) << 3)));
      }
#pragma unroll
      for (int fm = 0; fm < 4; ++fm)
#pragma unroll
        for (int fn = 0; fn < 4; ++fn)
          accu[fm][fn] = __builtin_amdgcn_mfma_f32_16x16x32_bf16(af[fm], bfr[fn],
                                                                 accu[fm][fn], 0, 0, 0);
    }
    __syncthreads();
  }

  // ---- epilogue: C/D layout col=lane&15, row=(lane>>4)*4+reg ----
#pragma unroll
  for (int fm = 0; fm < 4; ++fm)
#pragma unroll
    for (int fn = 0; fn < 4; ++fn)
#pragma unroll
      for (int rr = 0; rr < 4; ++rr) {
        const int row = wm + fm * 16 + q * 4 + rr;
        const int col = wn + fn * 16 + l15;
        const int gm = blockIdx.y * 128 + row;
        const int gn = blockIdx.x * 128 + col;
        const float g = accg[fm][fn][rr];
        const float u = accu[fm][fn][rr];
        const float s = g / (1.f + __expf(-g));  // silu in f32
        inter[(size_t)(seg + gm) * I_DIM + gn] = f2bf(s * u);
      }
}

// ---------------------------------------------------------------------------
// K6: down grouped GEMM (m97 structure), scatters fp32 rows to outp by token.
// A = inter bf16 [PAD_ROWS][I_DIM] (k-contiguous, no gather: segment rows).
// Bt = bf16 [E][H_DIM][I_DIM] pre-transposed (k-contiguous).
// ---------------------------------------------------------------------------
__global__ __launch_bounds__(256) void moe_gemm_down(
    const unsigned short* __restrict__ A,
    const unsigned short* __restrict__ Bt,
    const int* __restrict__ hdr,
    const int* __restrict__ rows,
    float* __restrict__ outp) {
  const int e = blockIdx.z;
  const int cnt = hdr[e];
  if ((int)blockIdx.y * 128 >= cnt) return;  // uniform early exit
  const int seg = hdr[16 + e];

  const int tid = threadIdx.x;
  const int lane = tid & 63;
  const int wv = tid >> 6;
  const int wm = (wv & 1) * 64;
  const int wn = (wv >> 1) * 64;
  const int q = lane >> 4;
  const int l15 = lane & 15;

  __shared__ unsigned short sA[128 * 64];
  __shared__ unsigned short sB[128 * 64];

  const int lr = lane >> 3;
  const int colsw = (lane & 7) ^ lr;
  const unsigned short* aptr[4];
  const unsigned short* bptr[4];
  const unsigned short* Be = Bt + (size_t)e * H_DIM * I_DIM;
#pragma unroll
  for (int j = 0; j < 4; ++j) {
    const int R = j * 32 + wv * 8 + lr;
    aptr[j] = A + (size_t)(seg + blockIdx.y * 128 + R) * I_DIM + colsw * 8;
    bptr[j] = Be + (size_t)(blockIdx.x * 128 + R) * I_DIM + colsw * 8;
  }

  floatx4 acc[4][4];
#pragma unroll
  for (int a = 0; a < 4; ++a)
#pragma unroll
    for (int b = 0; b < 4; ++b) acc[a][b] = (floatx4){0.f, 0.f, 0.f, 0.f};

  for (int kt = 0; kt < I_DIM; kt += 64) {
#pragma unroll
    for (int j = 0; j < 4; ++j) {
      gload_lds16(aptr[j] + kt, sA + (j * 32 + wv * 8) * 64);
      gload_lds16(bptr[j] + kt, sB + (j * 32 + wv * 8) * 64);
    }
    __syncthreads();
#pragma unroll
    for (int ks = 0; ks < 64; ks += 32) {
      const int sbase = ks >> 3;
      bf16x8 af[4], bfr[4];
#pragma unroll
      for (int fm = 0; fm < 4; ++fm) {
        const int ra = wm + fm * 16 + l15;
        af[fm] = __builtin_bit_cast(bf16x8,
            *(const ushort8*)(sA + ra * 64 + (((q + sbase) ^ (ra & 7)) << 3)));
      }
#pragma unroll
      for (int fn = 0; fn < 4; ++fn) {
        const int rb = wn + fn * 16 + l15;
        bfr[fn] = __builtin_bit_cast(bf16x8,
            *(const ushort8*)(sB + rb * 64 + (((q + sbase) ^ (rb & 7)) << 3)));
      }
#pragma unroll
      for (int fm = 0; fm < 4; ++fm)
#pragma unroll
        for (int fn = 0; fn < 4; ++fn)
          acc[fm][fn] = __builtin_amdgcn_mfma_f32_16x16x32_bf16(af[fm], bfr[fn],
                                                                acc[fm][fn], 0, 0, 0);
    }
    __syncthreads();
  }

#pragma unroll
  for (int fm = 0; fm < 4; ++fm)
#pragma unroll
    for (int fn = 0; fn < 4; ++fn)
#pragma unroll
      for (int rr = 0; rr < 4; ++rr) {
        const int row = wm + fm * 16 + q * 4 + rr;
        const int col = wn + fn * 16 + l15;
        const int gm = blockIdx.y * 128 + row;
        const int gn = blockIdx.x * 128 + col;
        const int tok = rows[seg + gm];
        if (tok >= 0) outp[(size_t)tok * H_DIM + gn] = acc[fm][fn][rr];
      }
}

// ---------------------------------------------------------------------------
// host launcher
// ---------------------------------------------------------------------------
extern "C" void kernel_launch(void* const* d_in, const int* in_sizes, int n_in,
                              void* d_out, int out_size, void* d_ws, size_t ws_size,
                              hipStream_t stream) {
  const float* hidden   = (const float*)d_in[0];
  const float* router_w = (const float*)d_in[1];
  const float* gate_w   = (const float*)d_in[2];
  const float* up_w     = (const float*)d_in[3];
  const float* down_w   = (const float*)d_in[4];
  float* out = (float*)d_out;

  char* ws = (char*)d_ws;
  // ws layout (bytes), with time-aliasing (stream-serial kernels):
  //   hdr   @ 0         : 32 ints
  //   idx   @ 1024      : 8192 ints            (32768 B)
  //   rows  @ 33792     : 9216 ints            (36864 B)
  //   x_bf  @ 70656     : 8192*2048 bf16       (33554432 B)
  //   inter @ 33625088  : 9216*4096 bf16       (75497472 B)
  //   W1    @ 109122560 : 134217728 B = gate_bt [8][4096][2048] bf16,
  //                       then (after fused GEMM) down_bt [8][2048][4096] bf16
  //   W2    @ 243340288 : 134217728 B = up_bt [8][4096][2048] bf16
  //   total = 377558016 B (~378 MB)
  int* hdr  = (int*)ws;
  int* idx  = (int*)(ws + 1024);
  int* rows = (int*)(ws + 33792);
  unsigned short* x_bf  = (unsigned short*)(ws + 70656);
  unsigned short* inter = (unsigned short*)(ws + 33625088);
  unsigned short* W1    = (unsigned short*)(ws + 109122560);
  unsigned short* W2    = (unsigned short*)(ws + 243340288);
  unsigned short* downt = W1;  // alias: gate_bt dead after fused GEMM

  xcvt_kernel<<<T_TOKENS * H_DIM / 1024, 256, 0, stream>>>(hidden, x_bf, hdr);
  router_kernel<<<T_TOKENS / 4, 256, 0, stream>>>(hidden, router_w, idx, hdr);
  setup_kernel<<<1, 256, 0, stream>>>(hdr, rows);
  scatter_kernel<<<T_TOKENS / 256, 256, 0, stream>>>(idx, hdr, rows);

  // weight prepasses (gate, up) — fp32 [K][N] -> bf16 [N][K]
  wtrans_kernel<H_DIM, I_DIM><<<dim3(I_DIM / 256, H_DIM / 64, E_EXP), 256, 0, stream>>>(gate_w, W1);
  wtrans_kernel<H_DIM, I_DIM><<<dim3(I_DIM / 256, H_DIM / 64, E_EXP), 256, 0, stream>>>(up_w, W2);

  // fused gate+up GEMM: inter = silu(x@gate) * (x@up)
  moe_gemm_gu<<<dim3(I_DIM / 128, 64, E_EXP), 256, 0, stream>>>(
      x_bf, W1, W2, hdr, rows, inter);

  // down prepass into W1 (gate_bt dead), then down GEMM scatters to out
  wtrans_kernel<I_DIM, H_DIM><<<dim3(H_DIM / 256, I_DIM / 64, E_EXP), 256, 0, stream>>>(down_w, downt);
  moe_gemm_down<<<dim3(H_DIM / 128, 64, E_EXP), 256, 0, stream>>>(
      inter, downt, hdr, rows, out);
}

// Round 3
// 1503.835 us; speedup vs baseline: 1.2170x; 1.0303x over previous
//
#include <hip/hip_runtime.h>
#include <hip/hip_bf16.h>

// Problem constants
#define T_TOKENS 8192   // SEQ*BS
#define H_DIM 2048
#define I_DIM 4096
#define E_EXP 8
#define PAD_ROWS 9216   // 8192 + 8*128 worst-case padded segment total

typedef __bf16 bf16x8 __attribute__((ext_vector_type(8)));
typedef float floatx4 __attribute__((ext_vector_type(4)));
typedef unsigned short ushort8 __attribute__((ext_vector_type(8)));

__device__ __forceinline__ unsigned short f2bf(float f) {
  // round-to-nearest-even f32 -> bf16 (inputs are finite; no NaN handling needed)
  union { float f; unsigned int i; } c; c.f = f;
  unsigned int x = c.i;
  unsigned int r = x + 0x7fffu + ((x >> 16) & 1u);
  return (unsigned short)(r >> 16);
}

__device__ __forceinline__ float bf2float(unsigned short u) {
  union { unsigned int i; float f; } c; c.i = ((unsigned int)u) << 16;
  return c.f;
}

// async global->LDS, 16B per lane. LDS dest = wave-uniform base + lane*16.
// Global source is PER-LANE -> swizzled layouts done by pre-swizzling the
// source address while keeping LDS linear (guide §5 / m173).
__device__ __forceinline__ void gload_lds16(const void* g, void* l) {
  __builtin_amdgcn_global_load_lds(
      (const __attribute__((address_space(1))) void*)g,
      (__attribute__((address_space(3))) void*)l, 16, 0, 0);
}

// ---------------------------------------------------------------------------
// K0: zero header + convert hidden_states fp32 -> bf16 (x_bf)
// ---------------------------------------------------------------------------
__global__ __launch_bounds__(256) void xcvt_kernel(const float* __restrict__ x,
                                                   unsigned short* __restrict__ xb,
                                                   int* __restrict__ hdr) {
  if (blockIdx.x == 0 && threadIdx.x < 32) hdr[threadIdx.x] = 0;
  int i = (blockIdx.x * 256 + threadIdx.x) * 4;
  floatx4 v = *(const floatx4*)(x + i);
  unsigned short o0 = f2bf(v[0]), o1 = f2bf(v[1]), o2 = f2bf(v[2]), o3 = f2bf(v[3]);
  ushort4 o; o.x = o0; o.y = o1; o.z = o2; o.w = o3;
  *(ushort4*)(xb + i) = o;
}

// ---------------------------------------------------------------------------
// K1: router logits + argmax (one wave per token), histogram via atomics
// hdr layout (ints): cnt[8] @0, cursor[8] @8, seg[8] @16
// ---------------------------------------------------------------------------
__global__ __launch_bounds__(256) void router_kernel(const float* __restrict__ x,
                                                     const float* __restrict__ rw,
                                                     int* __restrict__ idx,
                                                     int* __restrict__ hdr) {
  int lane = threadIdx.x & 63;
  int t = blockIdx.x * 4 + (threadIdx.x >> 6);
  const float* xr = x + (size_t)t * H_DIM;
  float acc[8];
#pragma unroll
  for (int e = 0; e < 8; ++e) acc[e] = 0.f;
  for (int i = lane; i < H_DIM; i += 64) {
    float h = xr[i];
    floatx4 r0 = *(const floatx4*)(rw + i * 8);
    floatx4 r1 = *(const floatx4*)(rw + i * 8 + 4);
#pragma unroll
    for (int e = 0; e < 4; ++e) { acc[e] += h * r0[e]; acc[e + 4] += h * r1[e]; }
  }
#pragma unroll
  for (int off = 32; off > 0; off >>= 1)
#pragma unroll
    for (int e = 0; e < 8; ++e) acc[e] += __shfl_xor(acc[e], off, 64);
  if (lane == 0) {
    int best = 0; float bv = acc[0];
#pragma unroll
    for (int e = 1; e < 8; ++e) if (acc[e] > bv) { bv = acc[e]; best = e; }
    idx[t] = best;
    atomicAdd(&hdr[best], 1);
  }
}

// ---------------------------------------------------------------------------
// K2: segment bases (128-aligned) + rows[] sentinel init
// ---------------------------------------------------------------------------
__global__ __launch_bounds__(256) void setup_kernel(int* __restrict__ hdr,
                                                    int* __restrict__ rows) {
  if (threadIdx.x == 0) {
    int b = 0;
    for (int e = 0; e < 8; ++e) {
      hdr[16 + e] = b;
      b += ((hdr[e] + 127) >> 7) << 7;
    }
  }
  for (int i = threadIdx.x; i < PAD_ROWS; i += 256) rows[i] = -1;
}

// ---------------------------------------------------------------------------
// K3: scatter token ids into per-expert segments
// ---------------------------------------------------------------------------
__global__ __launch_bounds__(256) void scatter_kernel(const int* __restrict__ idx,
                                                      int* __restrict__ hdr,
                                                      int* __restrict__ rows) {
  int t = blockIdx.x * 256 + threadIdx.x;
  int e = idx[t];
  int p = atomicAdd(&hdr[8 + e], 1);
  rows[hdr[16 + e] + p] = t;
}

// ---------------------------------------------------------------------------
// K4: weight prepass — fp32 W[e][K][N] -> bf16 Wt[e][N][K] (convert+transpose)
// Previous versions (scalar-LDS-read and pure-register) were both ~4x over
// the BW roofline; real bottleneck was the transposed WRITE: 16-32B per lane
// scattered at 4-8KB stride -> partial 128B lines, poor L2 merge, ~8x write
// amplification. This version exchanges through LDS so global stores are
// FULL 128B lines (8 consecutive lanes cover one line):
//   Phase 1: coalesced float4 loads; per-thread 4x4 register transpose
//     (static indices); ds_write_b64 into [n][k] tile with 16B-slot XOR
//     swizzle phys16 = slot ^ (n&7). (b64-write at the 4-lanes/bank floor.)
//   Phase 2: ds_read_b128 (8 lanes/4-bank group = floor) + coalesced 16B
//     stores, lanes (n=tid>>3, kc=tid&7) -> one full line per 8 lanes.
// Tile 64(k) x 64(n), 256 threads; grid (N/64, K/64, E).
// ---------------------------------------------------------------------------
template <int K, int N>
__global__ __launch_bounds__(256) void wtrans_kernel(const float* __restrict__ W,
                                                     unsigned short* __restrict__ Wt) {
  __shared__ unsigned short tile[64 * 64];  // [n][k] bf16, slot-swizzled (8KB)
  const int e = blockIdx.z;
  const int bn = blockIdx.x * 64;
  const int bk = blockIdx.y * 64;
  const float* Wp = W + (size_t)e * K * N + (size_t)bk * N + bn;
  unsigned short* Wtp = Wt + (size_t)e * N * K + (size_t)bn * K + bk;
  const int tid = threadIdx.x;

  {
    const int kq = tid >> 4;   // 0..15: k-quad
    const int nq = tid & 15;   // 0..15: n-quad
    floatx4 v[4];
#pragma unroll
    for (int i = 0; i < 4; ++i)
      v[i] = *(const floatx4*)(Wp + (size_t)(kq * 4 + i) * N + nq * 4);
    const int s16 = kq >> 1;   // logical 16B slot (holds k = s16*8 .. +7)
    const int half = kq & 1;   // which 8B half of the slot
#pragma unroll
    for (int j = 0; j < 4; ++j) {
      const int n = nq * 4 + j;
      ushort4 t;
      t.x = f2bf(v[0][j]); t.y = f2bf(v[1][j]);
      t.z = f2bf(v[2][j]); t.w = f2bf(v[3][j]);
      *(ushort4*)(tile + n * 64 + ((s16 ^ (n & 7)) << 3) + half * 4) = t;
    }
  }
  __syncthreads();
  {
    const int kc = tid & 7;    // 16B k-chunk
    const int nr = tid >> 3;   // 0..31
#pragma unroll
    for (int it = 0; it < 2; ++it) {
      const int n = it * 32 + nr;
      ushort8 o = *(const ushort8*)(tile + n * 64 + ((kc ^ (n & 7)) << 3));
      *(ushort8*)(Wtp + (size_t)n * K + kc * 8) = o;
    }
  }
}

// ---------------------------------------------------------------------------
// K5: fused gate+up grouped GEMM. 128x128 tile, BK=64, 256 threads = 4 waves,
// each wave 64x64 via 4x4 frags of mfma_f32_16x16x32_bf16, TWO accumulator
// sets (gate, up). A staged once per k-tile, both B tiles staged -> 32 MFMA
// per barrier pair. Epilogue: inter = silu(g_f32) * u.
// Staging: global_load_lds width=16, XOR-swizzled via pre-swizzled per-lane
// SOURCE (linear LDS dest) + matching swizzle on ds_read_b128:
//   phys16Bslot(row, slot) = slot ^ (row & 7)
// ---------------------------------------------------------------------------
__global__ __launch_bounds__(256, 2) void moe_gemm_gu(
    const unsigned short* __restrict__ A,
    const unsigned short* __restrict__ Bg,
    const unsigned short* __restrict__ Bu,
    const int* __restrict__ hdr,
    const int* __restrict__ rows,
    unsigned short* __restrict__ inter) {
  const int e = blockIdx.z;
  const int cnt = hdr[e];
  if ((int)blockIdx.y * 128 >= cnt) return;  // uniform early exit
  const int seg = hdr[16 + e];

  const int tid = threadIdx.x;
  const int lane = tid & 63;
  const int wv = tid >> 6;
  const int wm = (wv & 1) * 64;
  const int wn = (wv >> 1) * 64;
  const int q = lane >> 4;
  const int l15 = lane & 15;

  __shared__ unsigned short sA[128 * 64];   // [m][64k] bf16, slot-swizzled
  __shared__ unsigned short sBg[128 * 64];  // [n][64k] gate
  __shared__ unsigned short sBu[128 * 64];  // [n][64k] up

  const int lr = lane >> 3;            // row within 8-row chunk == row&7
  const int colsw = (lane & 7) ^ lr;   // pre-swizzled 8-elem slot index
  const unsigned short* aptr[4];
  const unsigned short* bgptr[4];
  const unsigned short* buptr[4];
  const unsigned short* BgE = Bg + (size_t)e * I_DIM * H_DIM;  // [N][K]
  const unsigned short* BuE = Bu + (size_t)e * I_DIM * H_DIM;
#pragma unroll
  for (int j = 0; j < 4; ++j) {
    const int R = j * 32 + wv * 8 + lr;
    int ar = rows[seg + blockIdx.y * 128 + R];
    if (ar < 0) ar = 0;  // padding rows: junk compute, dropped downstream
    aptr[j] = A + (size_t)ar * H_DIM + colsw * 8;
    bgptr[j] = BgE + (size_t)(blockIdx.x * 128 + R) * H_DIM + colsw * 8;
    buptr[j] = BuE + (size_t)(blockIdx.x * 128 + R) * H_DIM + colsw * 8;
  }

  floatx4 accg[4][4], accu[4][4];
#pragma unroll
  for (int a = 0; a < 4; ++a)
#pragma unroll
    for (int b = 0; b < 4; ++b) {
      accg[a][b] = (floatx4){0.f, 0.f, 0.f, 0.f};
      accu[a][b] = (floatx4){0.f, 0.f, 0.f, 0.f};
    }

  for (int kt = 0; kt < H_DIM; kt += 64) {
#pragma unroll
    for (int j = 0; j < 4; ++j) {
      gload_lds16(aptr[j] + kt, sA + (j * 32 + wv * 8) * 64);
      gload_lds16(bgptr[j] + kt, sBg + (j * 32 + wv * 8) * 64);
      gload_lds16(buptr[j] + kt, sBu + (j * 32 + wv * 8) * 64);
    }
    __syncthreads();  // compiler inserts vmcnt(0): DMA complete for all waves
#pragma unroll
    for (int ks = 0; ks < 64; ks += 32) {
      const int sbase = ks >> 3;  // 0 or 4 (8-elem slot units)
      bf16x8 af[4], bfr[4];
#pragma unroll
      for (int fm = 0; fm < 4; ++fm) {
        const int ra = wm + fm * 16 + l15;
        af[fm] = __builtin_bit_cast(bf16x8,
            *(const ushort8*)(sA + ra * 64 + (((q + sbase) ^ (ra & 7)) << 3)));
      }
#pragma unroll
      for (int fn = 0; fn < 4; ++fn) {
        const int rb = wn + fn * 16 + l15;
        bfr[fn] = __builtin_bit_cast(bf16x8,
            *(const ushort8*)(sBg + rb * 64 + (((q + sbase) ^ (rb & 7)) << 3)));
      }
#pragma unroll
      for (int fm = 0; fm < 4; ++fm)
#pragma unroll
        for (int fn = 0; fn < 4; ++fn)
          accg[fm][fn] = __builtin_amdgcn_mfma_f32_16x16x32_bf16(af[fm], bfr[fn],
                                                                 accg[fm][fn], 0, 0, 0);
#pragma unroll
      for (int fn = 0; fn < 4; ++fn) {
        const int rb = wn + fn * 16 + l15;
        bfr[fn] = __builtin_bit_cast(bf16x8,
            *(const ushort8*)(sBu + rb * 64 + (((q + sbase) ^ (rb & 7)) << 3)));
      }
#pragma unroll
      for (int fm = 0; fm < 4; ++fm)
#pragma unroll
        for (int fn = 0; fn < 4; ++fn)
          accu[fm][fn] = __builtin_amdgcn_mfma_f32_16x16x32_bf16(af[fm], bfr[fn],
                                                                 accu[fm][fn], 0, 0, 0);
    }
    __syncthreads();
  }

  // ---- epilogue: C/D layout col=lane&15, row=(lane>>4)*4+reg ----
#pragma unroll
  for (int fm = 0; fm < 4; ++fm)
#pragma unroll
    for (int fn = 0; fn < 4; ++fn)
#pragma unroll
      for (int rr = 0; rr < 4; ++rr) {
        const int row = wm + fm * 16 + q * 4 + rr;
        const int col = wn + fn * 16 + l15;
        const int gm = blockIdx.y * 128 + row;
        const int gn = blockIdx.x * 128 + col;
        const float g = accg[fm][fn][rr];
        const float u = accu[fm][fn][rr];
        const float s = g / (1.f + __expf(-g));  // silu in f32
        inter[(size_t)(seg + gm) * I_DIM + gn] = f2bf(s * u);
      }
}

// ---------------------------------------------------------------------------
// K6: down grouped GEMM, gu-style 2-way n-fusion: block computes 128m x 256n
// (two B n-tiles share one staged A) -> 32 MFMA per barrier pair.
// A = inter bf16 [PAD_ROWS][I_DIM] (k-contiguous, segment rows, no gather).
// Bt = bf16 [E][H_DIM][I_DIM] pre-transposed. Scatters fp32 rows by token.
// ---------------------------------------------------------------------------
__global__ __launch_bounds__(256, 2) void moe_gemm_down(
    const unsigned short* __restrict__ A,
    const unsigned short* __restrict__ Bt,
    const int* __restrict__ hdr,
    const int* __restrict__ rows,
    float* __restrict__ outp) {
  const int e = blockIdx.z;
  const int cnt = hdr[e];
  if ((int)blockIdx.y * 128 >= cnt) return;  // uniform early exit
  const int seg = hdr[16 + e];

  const int tid = threadIdx.x;
  const int lane = tid & 63;
  const int wv = tid >> 6;
  const int wm = (wv & 1) * 64;
  const int wn = (wv >> 1) * 64;
  const int q = lane >> 4;
  const int l15 = lane & 15;

  __shared__ unsigned short sA[128 * 64];
  __shared__ unsigned short sB0[128 * 64];
  __shared__ unsigned short sB1[128 * 64];

  const int lr = lane >> 3;
  const int colsw = (lane & 7) ^ lr;
  const unsigned short* aptr[4];
  const unsigned short* b0ptr[4];
  const unsigned short* b1ptr[4];
  const unsigned short* Be = Bt + (size_t)e * H_DIM * I_DIM;
#pragma unroll
  for (int j = 0; j < 4; ++j) {
    const int R = j * 32 + wv * 8 + lr;
    aptr[j]  = A + (size_t)(seg + blockIdx.y * 128 + R) * I_DIM + colsw * 8;
    b0ptr[j] = Be + (size_t)(blockIdx.x * 256 + R) * I_DIM + colsw * 8;
    b1ptr[j] = Be + (size_t)(blockIdx.x * 256 + 128 + R) * I_DIM + colsw * 8;
  }

  floatx4 acc0[4][4], acc1[4][4];
#pragma unroll
  for (int a = 0; a < 4; ++a)
#pragma unroll
    for (int b = 0; b < 4; ++b) {
      acc0[a][b] = (floatx4){0.f, 0.f, 0.f, 0.f};
      acc1[a][b] = (floatx4){0.f, 0.f, 0.f, 0.f};
    }

  for (int kt = 0; kt < I_DIM; kt += 64) {
#pragma unroll
    for (int j = 0; j < 4; ++j) {
      gload_lds16(aptr[j] + kt, sA + (j * 32 + wv * 8) * 64);
      gload_lds16(b0ptr[j] + kt, sB0 + (j * 32 + wv * 8) * 64);
      gload_lds16(b1ptr[j] + kt, sB1 + (j * 32 + wv * 8) * 64);
    }
    __syncthreads();
#pragma unroll
    for (int ks = 0; ks < 64; ks += 32) {
      const int sbase = ks >> 3;
      bf16x8 af[4], bfr[4];
#pragma unroll
      for (int fm = 0; fm < 4; ++fm) {
        const int ra = wm + fm * 16 + l15;
        af[fm] = __builtin_bit_cast(bf16x8,
            *(const ushort8*)(sA + ra * 64 + (((q + sbase) ^ (ra & 7)) << 3)));
      }
#pragma unroll
      for (int fn = 0; fn < 4; ++fn) {
        const int rb = wn + fn * 16 + l15;
        bfr[fn] = __builtin_bit_cast(bf16x8,
            *(const ushort8*)(sB0 + rb * 64 + (((q + sbase) ^ (rb & 7)) << 3)));
      }
#pragma unroll
      for (int fm = 0; fm < 4; ++fm)
#pragma unroll
        for (int fn = 0; fn < 4; ++fn)
          acc0[fm][fn] = __builtin_amdgcn_mfma_f32_16x16x32_bf16(af[fm], bfr[fn],
                                                                 acc0[fm][fn], 0, 0, 0);
#pragma unroll
      for (int fn = 0; fn < 4; ++fn) {
        const int rb = wn + fn * 16 + l15;
        bfr[fn] = __builtin_bit_cast(bf16x8,
            *(const ushort8*)(sB1 + rb * 64 + (((q + sbase) ^ (rb & 7)) << 3)));
      }
#pragma unroll
      for (int fm = 0; fm < 4; ++fm)
#pragma unroll
        for (int fn = 0; fn < 4; ++fn)
          acc1[fm][fn] = __builtin_amdgcn_mfma_f32_16x16x32_bf16(af[fm], bfr[fn],
                                                                 acc1[fm][fn], 0, 0, 0);
    }
    __syncthreads();
  }

  // ---- epilogue: scatter both n-halves by token ----
#pragma unroll
  for (int fm = 0; fm < 4; ++fm)
#pragma unroll
    for (int rr = 0; rr < 4; ++rr) {
      const int row = wm + fm * 16 + q * 4 + rr;
      const int tok = rows[seg + blockIdx.y * 128 + row];
      if (tok < 0) continue;
      float* orow = outp + (size_t)tok * H_DIM + blockIdx.x * 256;
#pragma unroll
      for (int fn = 0; fn < 4; ++fn) {
        const int col = wn + fn * 16 + l15;
        orow[col]       = acc0[fm][fn][rr];
        orow[128 + col] = acc1[fm][fn][rr];
      }
    }
}

// ---------------------------------------------------------------------------
// host launcher
// ---------------------------------------------------------------------------
extern "C" void kernel_launch(void* const* d_in, const int* in_sizes, int n_in,
                              void* d_out, int out_size, void* d_ws, size_t ws_size,
                              hipStream_t stream) {
  const float* hidden   = (const float*)d_in[0];
  const float* router_w = (const float*)d_in[1];
  const float* gate_w   = (const float*)d_in[2];
  const float* up_w     = (const float*)d_in[3];
  const float* down_w   = (const float*)d_in[4];
  float* out = (float*)d_out;

  char* ws = (char*)d_ws;
  // ws layout (bytes), with time-aliasing (stream-serial kernels):
  //   hdr   @ 0         : 32 ints
  //   idx   @ 1024      : 8192 ints            (32768 B)
  //   rows  @ 33792     : 9216 ints            (36864 B)
  //   x_bf  @ 70656     : 8192*2048 bf16       (33554432 B)
  //   inter @ 33625088  : 9216*4096 bf16       (75497472 B)
  //   W1    @ 109122560 : 134217728 B = gate_bt [8][4096][2048] bf16,
  //                       then (after fused GEMM) down_bt [8][2048][4096] bf16
  //   W2    @ 243340288 : 134217728 B = up_bt [8][4096][2048] bf16
  //   total = 377558016 B (~378 MB)
  int* hdr  = (int*)ws;
  int* idx  = (int*)(ws + 1024);
  int* rows = (int*)(ws + 33792);
  unsigned short* x_bf  = (unsigned short*)(ws + 70656);
  unsigned short* inter = (unsigned short*)(ws + 33625088);
  unsigned short* W1    = (unsigned short*)(ws + 109122560);
  unsigned short* W2    = (unsigned short*)(ws + 243340288);
  unsigned short* downt = W1;  // alias: gate_bt dead after fused GEMM

  xcvt_kernel<<<T_TOKENS * H_DIM / 1024, 256, 0, stream>>>(hidden, x_bf, hdr);
  router_kernel<<<T_TOKENS / 4, 256, 0, stream>>>(hidden, router_w, idx, hdr);
  setup_kernel<<<1, 256, 0, stream>>>(hdr, rows);
  scatter_kernel<<<T_TOKENS / 256, 256, 0, stream>>>(idx, hdr, rows);

  // weight prepasses (gate, up) — fp32 [K][N] -> bf16 [N][K]
  wtrans_kernel<H_DIM, I_DIM><<<dim3(I_DIM / 64, H_DIM / 64, E_EXP), 256, 0, stream>>>(gate_w, W1);
  wtrans_kernel<H_DIM, I_DIM><<<dim3(I_DIM / 64, H_DIM / 64, E_EXP), 256, 0, stream>>>(up_w, W2);

  // fused gate+up GEMM: inter = silu(x@gate) * (x@up)
  moe_gemm_gu<<<dim3(I_DIM / 128, 64, E_EXP), 256, 0, stream>>>(
      x_bf, W1, W2, hdr, rows, inter);

  // down prepass into W1 (gate_bt dead), then down GEMM scatters to out
  wtrans_kernel<I_DIM, H_DIM><<<dim3(H_DIM / 64, I_DIM / 64, E_EXP), 256, 0, stream>>>(down_w, downt);
  moe_gemm_down<<<dim3(H_DIM / 256, 64, E_EXP), 256, 0, stream>>>(
      inter, downt, hdr, rows, out);
}

// Round 4
// 1499.267 us; speedup vs baseline: 1.2207x; 1.0030x over previous
//
#include <hip/hip_runtime.h>
#include <hip/hip_bf16.h>

// Problem constants
#define T_TOKENS 8192   // SEQ*BS
#define H_DIM 2048
#define I_DIM 4096
#define E_EXP 8
#define PAD_ROWS 9216   // 8192 + 8*128 worst-case padded segment total

typedef __bf16 bf16x8 __attribute__((ext_vector_type(8)));
typedef float floatx4 __attribute__((ext_vector_type(4)));
typedef unsigned short ushort8 __attribute__((ext_vector_type(8)));

__device__ __forceinline__ unsigned short f2bf(float f) {
  // round-to-nearest-even f32 -> bf16 (inputs are finite; no NaN handling needed)
  union { float f; unsigned int i; } c; c.f = f;
  unsigned int x = c.i;
  unsigned int r = x + 0x7fffu + ((x >> 16) & 1u);
  return (unsigned short)(r >> 16);
}

__device__ __forceinline__ float bf2float(unsigned short u) {
  union { unsigned int i; float f; } c; c.i = ((unsigned int)u) << 16;
  return c.f;
}

// async global->LDS, 16B per lane. LDS dest = wave-uniform base + lane*16.
// Global source is PER-LANE -> swizzled layouts done by pre-swizzling the
// source address while keeping LDS linear (guide §5 / m173).
__device__ __forceinline__ void gload_lds16(const void* g, void* l) {
  __builtin_amdgcn_global_load_lds(
      (const __attribute__((address_space(1))) void*)g,
      (__attribute__((address_space(3))) void*)l, 16, 0, 0);
}

// ---------------------------------------------------------------------------
// K0: zero header + convert hidden_states fp32 -> bf16 (x_bf)
// ---------------------------------------------------------------------------
__global__ __launch_bounds__(256) void xcvt_kernel(const float* __restrict__ x,
                                                   unsigned short* __restrict__ xb,
                                                   int* __restrict__ hdr) {
  if (blockIdx.x == 0 && threadIdx.x < 32) hdr[threadIdx.x] = 0;
  int i = (blockIdx.x * 256 + threadIdx.x) * 4;
  floatx4 v = *(const floatx4*)(x + i);
  unsigned short o0 = f2bf(v[0]), o1 = f2bf(v[1]), o2 = f2bf(v[2]), o3 = f2bf(v[3]);
  ushort4 o; o.x = o0; o.y = o1; o.z = o2; o.w = o3;
  *(ushort4*)(xb + i) = o;
}

// ---------------------------------------------------------------------------
// K1: router logits + argmax (one wave per token), histogram via atomics
// hdr layout (ints): cnt[8] @0, cursor[8] @8, seg[8] @16
// ---------------------------------------------------------------------------
__global__ __launch_bounds__(256) void router_kernel(const float* __restrict__ x,
                                                     const float* __restrict__ rw,
                                                     int* __restrict__ idx,
                                                     int* __restrict__ hdr) {
  int lane = threadIdx.x & 63;
  int t = blockIdx.x * 4 + (threadIdx.x >> 6);
  const float* xr = x + (size_t)t * H_DIM;
  float acc[8];
#pragma unroll
  for (int e = 0; e < 8; ++e) acc[e] = 0.f;
  for (int i = lane; i < H_DIM; i += 64) {
    float h = xr[i];
    floatx4 r0 = *(const floatx4*)(rw + i * 8);
    floatx4 r1 = *(const floatx4*)(rw + i * 8 + 4);
#pragma unroll
    for (int e = 0; e < 4; ++e) { acc[e] += h * r0[e]; acc[e + 4] += h * r1[e]; }
  }
#pragma unroll
  for (int off = 32; off > 0; off >>= 1)
#pragma unroll
    for (int e = 0; e < 8; ++e) acc[e] += __shfl_xor(acc[e], off, 64);
  if (lane == 0) {
    int best = 0; float bv = acc[0];
#pragma unroll
    for (int e = 1; e < 8; ++e) if (acc[e] > bv) { bv = acc[e]; best = e; }
    idx[t] = best;
    atomicAdd(&hdr[best], 1);
  }
}

// ---------------------------------------------------------------------------
// K2: segment bases (128-aligned) + rows[] sentinel init
// ---------------------------------------------------------------------------
__global__ __launch_bounds__(256) void setup_kernel(int* __restrict__ hdr,
                                                    int* __restrict__ rows) {
  if (threadIdx.x == 0) {
    int b = 0;
    for (int e = 0; e < 8; ++e) {
      hdr[16 + e] = b;
      b += ((hdr[e] + 127) >> 7) << 7;
    }
  }
  for (int i = threadIdx.x; i < PAD_ROWS; i += 256) rows[i] = -1;
}

// ---------------------------------------------------------------------------
// K3: scatter token ids into per-expert segments
// ---------------------------------------------------------------------------
__global__ __launch_bounds__(256) void scatter_kernel(const int* __restrict__ idx,
                                                      int* __restrict__ hdr,
                                                      int* __restrict__ rows) {
  int t = blockIdx.x * 256 + threadIdx.x;
  int e = idx[t];
  int p = atomicAdd(&hdr[8 + e], 1);
  rows[hdr[16 + e] + p] = t;
}

// ---------------------------------------------------------------------------
// K4: weight prepass — fp32 W[e][K][N] -> bf16 Wt[e][N][K] (convert+transpose)
// v4: prior versions (64x64 tiles) were ~4x over the BW roofline regardless
// of LDS strategy -> diagnosis: global access GRANULARITY. 256B reads /
// 128B writes at 4-16KB stride from ~20 resident blocks/CU = near-random
// small requests to DRAM. This version: 256(k) x 128(n) tile so every
// global transaction stream is 512B contiguous, and 64KB LDS -> only 2
// blocks/CU -> few long streams per CU.
//   Phase A: 8 passes; thread (kq,nq) loads 4 float4 (32 lanes = 512B/row),
//     4x4 register transpose, 4x ds_write_b64 into [128n][256k] tile with
//     16B-slot XOR swizzle phys = s ^ (n>>2)  (b64 write at 4-lane/bank-pair
//     floor; reads conflict-free).
//   Phase B: 16 passes; ds_read_b128 + 512B-contiguous global stores
//     (32 lanes x 16B per output row).
// Grid (N/128, K/256, E) = 2048 blocks per matrix.
// ---------------------------------------------------------------------------
template <int K, int N>
__global__ __launch_bounds__(256) void wtrans_kernel(const float* __restrict__ W,
                                                     unsigned short* __restrict__ Wt) {
  __shared__ unsigned short tile[128 * 256];  // [n][k] bf16, slot-swizzled (64KB)
  const int e = blockIdx.z;
  const int bn = blockIdx.x * 128;
  const int bk = blockIdx.y * 256;
  const float* Wp = W + (size_t)e * K * N + (size_t)bk * N + bn;
  unsigned short* Wtp = Wt + (size_t)e * N * K + (size_t)bn * K + bk;
  const int tid = threadIdx.x;

  // ---- Phase A: load + register-transpose + swizzled LDS write ----
  {
    const int nq = tid & 31;        // n-quad: n = nq*4+j
    const int kqb = tid >> 5;       // 0..7
#pragma unroll
    for (int pass = 0; pass < 8; ++pass) {
      const int kq = (pass & 1) * 8 + kqb;          // 0..15
      const int kc = pass >> 1;                     // 0..3 (64-k chunk)
      const int krow = kc * 64 + kq * 4;            // k within block, mult of 4
      const float* src = Wp + (size_t)krow * N + nq * 4;
      floatx4 v0 = *(const floatx4*)(src);
      floatx4 v1 = *(const floatx4*)(src + (size_t)N);
      floatx4 v2 = *(const floatx4*)(src + (size_t)2 * N);
      floatx4 v3 = *(const floatx4*)(src + (size_t)3 * N);
      const int s = krow >> 3;                      // logical 16B slot (0..31)
      const int half = (krow >> 2) & 1;             // 8B half within slot
      const int phys = s ^ nq;                      // nq == n>>2 for j<4
#pragma unroll
      for (int j = 0; j < 4; ++j) {
        const int n = nq * 4 + j;
        ushort4 t;
        t.x = f2bf(v0[j]); t.y = f2bf(v1[j]);
        t.z = f2bf(v2[j]); t.w = f2bf(v3[j]);
        *(ushort4*)(tile + n * 256 + phys * 8 + half * 4) = t;
      }
    }
  }
  __syncthreads();
  // ---- Phase B: wide LDS read + 512B-contiguous global store ----
  {
    const int sl = tid & 31;        // logical 16B k-slot
    const int nb = tid >> 5;        // 0..7
#pragma unroll
    for (int pass = 0; pass < 16; ++pass) {
      const int n = pass * 8 + nb;
      const int phys = sl ^ ((n >> 2) & 31);
      ushort8 o = *(const ushort8*)(tile + n * 256 + phys * 8);
      *(ushort8*)(Wtp + (size_t)n * K + sl * 8) = o;
    }
  }
}

// ---------------------------------------------------------------------------
// K5: fused gate+up grouped GEMM. 128x128 tile, BK=64, 256 threads = 4 waves,
// each wave 64x64 via 4x4 frags of mfma_f32_16x16x32_bf16, TWO accumulator
// sets (gate, up). A staged once per k-tile, both B tiles staged -> 32 MFMA
// per barrier pair. Epilogue: inter = silu(g_f32) * u.
// Staging: global_load_lds width=16, XOR-swizzled via pre-swizzled per-lane
// SOURCE (linear LDS dest) + matching swizzle on ds_read_b128:
//   phys16Bslot(row, slot) = slot ^ (row & 7)
// ---------------------------------------------------------------------------
__global__ __launch_bounds__(256, 2) void moe_gemm_gu(
    const unsigned short* __restrict__ A,
    const unsigned short* __restrict__ Bg,
    const unsigned short* __restrict__ Bu,
    const int* __restrict__ hdr,
    const int* __restrict__ rows,
    unsigned short* __restrict__ inter) {
  const int e = blockIdx.z;
  const int cnt = hdr[e];
  if ((int)blockIdx.y * 128 >= cnt) return;  // uniform early exit
  const int seg = hdr[16 + e];

  const int tid = threadIdx.x;
  const int lane = tid & 63;
  const int wv = tid >> 6;
  const int wm = (wv & 1) * 64;
  const int wn = (wv >> 1) * 64;
  const int q = lane >> 4;
  const int l15 = lane & 15;

  __shared__ unsigned short sA[128 * 64];   // [m][64k] bf16, slot-swizzled
  __shared__ unsigned short sBg[128 * 64];  // [n][64k] gate
  __shared__ unsigned short sBu[128 * 64];  // [n][64k] up

  const int lr = lane >> 3;            // row within 8-row chunk == row&7
  const int colsw = (lane & 7) ^ lr;   // pre-swizzled 8-elem slot index
  const unsigned short* aptr[4];
  const unsigned short* bgptr[4];
  const unsigned short* buptr[4];
  const unsigned short* BgE = Bg + (size_t)e * I_DIM * H_DIM;  // [N][K]
  const unsigned short* BuE = Bu + (size_t)e * I_DIM * H_DIM;
#pragma unroll
  for (int j = 0; j < 4; ++j) {
    const int R = j * 32 + wv * 8 + lr;
    int ar = rows[seg + blockIdx.y * 128 + R];
    if (ar < 0) ar = 0;  // padding rows: junk compute, dropped downstream
    aptr[j] = A + (size_t)ar * H_DIM + colsw * 8;
    bgptr[j] = BgE + (size_t)(blockIdx.x * 128 + R) * H_DIM + colsw * 8;
    buptr[j] = BuE + (size_t)(blockIdx.x * 128 + R) * H_DIM + colsw * 8;
  }

  floatx4 accg[4][4], accu[4][4];
#pragma unroll
  for (int a = 0; a < 4; ++a)
#pragma unroll
    for (int b = 0; b < 4; ++b) {
      accg[a][b] = (floatx4){0.f, 0.f, 0.f, 0.f};
      accu[a][b] = (floatx4){0.f, 0.f, 0.f, 0.f};
    }

  for (int kt = 0; kt < H_DIM; kt += 64) {
#pragma unroll
    for (int j = 0; j < 4; ++j) {
      gload_lds16(aptr[j] + kt, sA + (j * 32 + wv * 8) * 64);
      gload_lds16(bgptr[j] + kt, sBg + (j * 32 + wv * 8) * 64);
      gload_lds16(buptr[j] + kt, sBu + (j * 32 + wv * 8) * 64);
    }
    __syncthreads();  // compiler inserts vmcnt(0): DMA complete for all waves
#pragma unroll
    for (int ks = 0; ks < 64; ks += 32) {
      const int sbase = ks >> 3;  // 0 or 4 (8-elem slot units)
      bf16x8 af[4], bfr[4];
#pragma unroll
      for (int fm = 0; fm < 4; ++fm) {
        const int ra = wm + fm * 16 + l15;
        af[fm] = __builtin_bit_cast(bf16x8,
            *(const ushort8*)(sA + ra * 64 + (((q + sbase) ^ (ra & 7)) << 3)));
      }
#pragma unroll
      for (int fn = 0; fn < 4; ++fn) {
        const int rb = wn + fn * 16 + l15;
        bfr[fn] = __builtin_bit_cast(bf16x8,
            *(const ushort8*)(sBg + rb * 64 + (((q + sbase) ^ (rb & 7)) << 3)));
      }
#pragma unroll
      for (int fm = 0; fm < 4; ++fm)
#pragma unroll
        for (int fn = 0; fn < 4; ++fn)
          accg[fm][fn] = __builtin_amdgcn_mfma_f32_16x16x32_bf16(af[fm], bfr[fn],
                                                                 accg[fm][fn], 0, 0, 0);
#pragma unroll
      for (int fn = 0; fn < 4; ++fn) {
        const int rb = wn + fn * 16 + l15;
        bfr[fn] = __builtin_bit_cast(bf16x8,
            *(const ushort8*)(sBu + rb * 64 + (((q + sbase) ^ (rb & 7)) << 3)));
      }
#pragma unroll
      for (int fm = 0; fm < 4; ++fm)
#pragma unroll
        for (int fn = 0; fn < 4; ++fn)
          accu[fm][fn] = __builtin_amdgcn_mfma_f32_16x16x32_bf16(af[fm], bfr[fn],
                                                                 accu[fm][fn], 0, 0, 0);
    }
    __syncthreads();
  }

  // ---- epilogue: C/D layout col=lane&15, row=(lane>>4)*4+reg ----
#pragma unroll
  for (int fm = 0; fm < 4; ++fm)
#pragma unroll
    for (int fn = 0; fn < 4; ++fn)
#pragma unroll
      for (int rr = 0; rr < 4; ++rr) {
        const int row = wm + fm * 16 + q * 4 + rr;
        const int col = wn + fn * 16 + l15;
        const int gm = blockIdx.y * 128 + row;
        const int gn = blockIdx.x * 128 + col;
        const float g = accg[fm][fn][rr];
        const float u = accu[fm][fn][rr];
        const float s = g / (1.f + __expf(-g));  // silu in f32
        inter[(size_t)(seg + gm) * I_DIM + gn] = f2bf(s * u);
      }
}

// ---------------------------------------------------------------------------
// K6: down grouped GEMM, gu-style 2-way n-fusion: block computes 128m x 256n
// (two B n-tiles share one staged A) -> 32 MFMA per barrier pair.
// A = inter bf16 [PAD_ROWS][I_DIM] (k-contiguous, segment rows, no gather).
// Bt = bf16 [E][H_DIM][I_DIM] pre-transposed. Scatters fp32 rows by token.
// ---------------------------------------------------------------------------
__global__ __launch_bounds__(256, 2) void moe_gemm_down(
    const unsigned short* __restrict__ A,
    const unsigned short* __restrict__ Bt,
    const int* __restrict__ hdr,
    const int* __restrict__ rows,
    float* __restrict__ outp) {
  const int e = blockIdx.z;
  const int cnt = hdr[e];
  if ((int)blockIdx.y * 128 >= cnt) return;  // uniform early exit
  const int seg = hdr[16 + e];

  const int tid = threadIdx.x;
  const int lane = tid & 63;
  const int wv = tid >> 6;
  const int wm = (wv & 1) * 64;
  const int wn = (wv >> 1) * 64;
  const int q = lane >> 4;
  const int l15 = lane & 15;

  __shared__ unsigned short sA[128 * 64];
  __shared__ unsigned short sB0[128 * 64];
  __shared__ unsigned short sB1[128 * 64];

  const int lr = lane >> 3;
  const int colsw = (lane & 7) ^ lr;
  const unsigned short* aptr[4];
  const unsigned short* b0ptr[4];
  const unsigned short* b1ptr[4];
  const unsigned short* Be = Bt + (size_t)e * H_DIM * I_DIM;
#pragma unroll
  for (int j = 0; j < 4; ++j) {
    const int R = j * 32 + wv * 8 + lr;
    aptr[j]  = A + (size_t)(seg + blockIdx.y * 128 + R) * I_DIM + colsw * 8;
    b0ptr[j] = Be + (size_t)(blockIdx.x * 256 + R) * I_DIM + colsw * 8;
    b1ptr[j] = Be + (size_t)(blockIdx.x * 256 + 128 + R) * I_DIM + colsw * 8;
  }

  floatx4 acc0[4][4], acc1[4][4];
#pragma unroll
  for (int a = 0; a < 4; ++a)
#pragma unroll
    for (int b = 0; b < 4; ++b) {
      acc0[a][b] = (floatx4){0.f, 0.f, 0.f, 0.f};
      acc1[a][b] = (floatx4){0.f, 0.f, 0.f, 0.f};
    }

  for (int kt = 0; kt < I_DIM; kt += 64) {
#pragma unroll
    for (int j = 0; j < 4; ++j) {
      gload_lds16(aptr[j] + kt, sA + (j * 32 + wv * 8) * 64);
      gload_lds16(b0ptr[j] + kt, sB0 + (j * 32 + wv * 8) * 64);
      gload_lds16(b1ptr[j] + kt, sB1 + (j * 32 + wv * 8) * 64);
    }
    __syncthreads();
#pragma unroll
    for (int ks = 0; ks < 64; ks += 32) {
      const int sbase = ks >> 3;
      bf16x8 af[4], bfr[4];
#pragma unroll
      for (int fm = 0; fm < 4; ++fm) {
        const int ra = wm + fm * 16 + l15;
        af[fm] = __builtin_bit_cast(bf16x8,
            *(const ushort8*)(sA + ra * 64 + (((q + sbase) ^ (ra & 7)) << 3)));
      }
#pragma unroll
      for (int fn = 0; fn < 4; ++fn) {
        const int rb = wn + fn * 16 + l15;
        bfr[fn] = __builtin_bit_cast(bf16x8,
            *(const ushort8*)(sB0 + rb * 64 + (((q + sbase) ^ (rb & 7)) << 3)));
      }
#pragma unroll
      for (int fm = 0; fm < 4; ++fm)
#pragma unroll
        for (int fn = 0; fn < 4; ++fn)
          acc0[fm][fn] = __builtin_amdgcn_mfma_f32_16x16x32_bf16(af[fm], bfr[fn],
                                                                 acc0[fm][fn], 0, 0, 0);
#pragma unroll
      for (int fn = 0; fn < 4; ++fn) {
        const int rb = wn + fn * 16 + l15;
        bfr[fn] = __builtin_bit_cast(bf16x8,
            *(const ushort8*)(sB1 + rb * 64 + (((q + sbase) ^ (rb & 7)) << 3)));
      }
#pragma unroll
      for (int fm = 0; fm < 4; ++fm)
#pragma unroll
        for (int fn = 0; fn < 4; ++fn)
          acc1[fm][fn] = __builtin_amdgcn_mfma_f32_16x16x32_bf16(af[fm], bfr[fn],
                                                                 acc1[fm][fn], 0, 0, 0);
    }
    __syncthreads();
  }

  // ---- epilogue: scatter both n-halves by token ----
#pragma unroll
  for (int fm = 0; fm < 4; ++fm)
#pragma unroll
    for (int rr = 0; rr < 4; ++rr) {
      const int row = wm + fm * 16 + q * 4 + rr;
      const int tok = rows[seg + blockIdx.y * 128 + row];
      if (tok < 0) continue;
      float* orow = outp + (size_t)tok * H_DIM + blockIdx.x * 256;
#pragma unroll
      for (int fn = 0; fn < 4; ++fn) {
        const int col = wn + fn * 16 + l15;
        orow[col]       = acc0[fm][fn][rr];
        orow[128 + col] = acc1[fm][fn][rr];
      }
    }
}

// ---------------------------------------------------------------------------
// host launcher
// ---------------------------------------------------------------------------
extern "C" void kernel_launch(void* const* d_in, const int* in_sizes, int n_in,
                              void* d_out, int out_size, void* d_ws, size_t ws_size,
                              hipStream_t stream) {
  const float* hidden   = (const float*)d_in[0];
  const float* router_w = (const float*)d_in[1];
  const float* gate_w   = (const float*)d_in[2];
  const float* up_w     = (const float*)d_in[3];
  const float* down_w   = (const float*)d_in[4];
  float* out = (float*)d_out;

  char* ws = (char*)d_ws;
  // ws layout (bytes), with time-aliasing (stream-serial kernels):
  //   hdr   @ 0         : 32 ints
  //   idx   @ 1024      : 8192 ints            (32768 B)
  //   rows  @ 33792     : 9216 ints            (36864 B)
  //   x_bf  @ 70656     : 8192*2048 bf16       (33554432 B)
  //   inter @ 33625088  : 9216*4096 bf16       (75497472 B)
  //   W1    @ 109122560 : 134217728 B = gate_bt [8][4096][2048] bf16,
  //                       then (after fused GEMM) down_bt [8][2048][4096] bf16
  //   W2    @ 243340288 : 134217728 B = up_bt [8][4096][2048] bf16
  //   total = 377558016 B (~378 MB)
  int* hdr  = (int*)ws;
  int* idx  = (int*)(ws + 1024);
  int* rows = (int*)(ws + 33792);
  unsigned short* x_bf  = (unsigned short*)(ws + 70656);
  unsigned short* inter = (unsigned short*)(ws + 33625088);
  unsigned short* W1    = (unsigned short*)(ws + 109122560);
  unsigned short* W2    = (unsigned short*)(ws + 243340288);
  unsigned short* downt = W1;  // alias: gate_bt dead after fused GEMM

  xcvt_kernel<<<T_TOKENS * H_DIM / 1024, 256, 0, stream>>>(hidden, x_bf, hdr);
  router_kernel<<<T_TOKENS / 4, 256, 0, stream>>>(hidden, router_w, idx, hdr);
  setup_kernel<<<1, 256, 0, stream>>>(hdr, rows);
  scatter_kernel<<<T_TOKENS / 256, 256, 0, stream>>>(idx, hdr, rows);

  // weight prepasses (gate, up) — fp32 [K][N] -> bf16 [N][K]
  wtrans_kernel<H_DIM, I_DIM><<<dim3(I_DIM / 128, H_DIM / 256, E_EXP), 256, 0, stream>>>(gate_w, W1);
  wtrans_kernel<H_DIM, I_DIM><<<dim3(I_DIM / 128, H_DIM / 256, E_EXP), 256, 0, stream>>>(up_w, W2);

  // fused gate+up GEMM: inter = silu(x@gate) * (x@up)
  moe_gemm_gu<<<dim3(I_DIM / 128, 64, E_EXP), 256, 0, stream>>>(
      x_bf, W1, W2, hdr, rows, inter);

  // down prepass into W1 (gate_bt dead), then down GEMM scatters to out
  wtrans_kernel<I_DIM, H_DIM><<<dim3(H_DIM / 128, I_DIM / 256, E_EXP), 256, 0, stream>>>(down_w, downt);
  moe_gemm_down<<<dim3(H_DIM / 256, 64, E_EXP), 256, 0, stream>>>(
      inter, downt, hdr, rows, out);
}

// Round 5
// 1497.377 us; speedup vs baseline: 1.2222x; 1.0013x over previous
//
#include <hip/hip_runtime.h>
#include <hip/hip_bf16.h>

// Problem constants
#define T_TOKENS 8192   // SEQ*BS
#define H_DIM 2048
#define I_DIM 4096
#define E_EXP 8
#define PAD_ROWS 9216   // 8192 + 8*128 worst-case padded segment total

typedef __bf16 bf16x8 __attribute__((ext_vector_type(8)));
typedef float floatx4 __attribute__((ext_vector_type(4)));
typedef unsigned short ushort8 __attribute__((ext_vector_type(8)));

__device__ __forceinline__ unsigned short f2bf(float f) {
  // round-to-nearest-even f32 -> bf16 (inputs are finite; no NaN handling needed)
  union { float f; unsigned int i; } c; c.f = f;
  unsigned int x = c.i;
  unsigned int r = x + 0x7fffu + ((x >> 16) & 1u);
  return (unsigned short)(r >> 16);
}

__device__ __forceinline__ float bf2float(unsigned short u) {
  union { unsigned int i; float f; } c; c.i = ((unsigned int)u) << 16;
  return c.f;
}

// async global->LDS, 16B per lane. LDS dest = wave-uniform base + lane*16.
// Global source is PER-LANE (guide §5 / m173).
__device__ __forceinline__ void gload_lds16(const void* g, void* l) {
  __builtin_amdgcn_global_load_lds(
      (const __attribute__((address_space(1))) void*)g,
      (__attribute__((address_space(3))) void*)l, 16, 0, 0);
}

// ---------------------------------------------------------------------------
// K0: zero header + convert hidden_states fp32 -> bf16 (x_bf)
// ---------------------------------------------------------------------------
__global__ __launch_bounds__(256) void xcvt_kernel(const float* __restrict__ x,
                                                   unsigned short* __restrict__ xb,
                                                   int* __restrict__ hdr) {
  if (blockIdx.x == 0 && threadIdx.x < 32) hdr[threadIdx.x] = 0;
  int i = (blockIdx.x * 256 + threadIdx.x) * 4;
  floatx4 v = *(const floatx4*)(x + i);
  unsigned short o0 = f2bf(v[0]), o1 = f2bf(v[1]), o2 = f2bf(v[2]), o3 = f2bf(v[3]);
  ushort4 o; o.x = o0; o.y = o1; o.z = o2; o.w = o3;
  *(ushort4*)(xb + i) = o;
}

// ---------------------------------------------------------------------------
// K1: router logits + argmax (one wave per token), histogram via atomics
// hdr layout (ints): cnt[8] @0, cursor[8] @8, seg[8] @16
// ---------------------------------------------------------------------------
__global__ __launch_bounds__(256) void router_kernel(const float* __restrict__ x,
                                                     const float* __restrict__ rw,
                                                     int* __restrict__ idx,
                                                     int* __restrict__ hdr) {
  int lane = threadIdx.x & 63;
  int t = blockIdx.x * 4 + (threadIdx.x >> 6);
  const float* xr = x + (size_t)t * H_DIM;
  float acc[8];
#pragma unroll
  for (int e = 0; e < 8; ++e) acc[e] = 0.f;
  for (int i = lane; i < H_DIM; i += 64) {
    float h = xr[i];
    floatx4 r0 = *(const floatx4*)(rw + i * 8);
    floatx4 r1 = *(const floatx4*)(rw + i * 8 + 4);
#pragma unroll
    for (int e = 0; e < 4; ++e) { acc[e] += h * r0[e]; acc[e + 4] += h * r1[e]; }
  }
#pragma unroll
  for (int off = 32; off > 0; off >>= 1)
#pragma unroll
    for (int e = 0; e < 8; ++e) acc[e] += __shfl_xor(acc[e], off, 64);
  if (lane == 0) {
    int best = 0; float bv = acc[0];
#pragma unroll
    for (int e = 1; e < 8; ++e) if (acc[e] > bv) { bv = acc[e]; best = e; }
    idx[t] = best;
    atomicAdd(&hdr[best], 1);
  }
}

// ---------------------------------------------------------------------------
// K2: segment bases (128-aligned) + rows[] sentinel init
// ---------------------------------------------------------------------------
__global__ __launch_bounds__(256) void setup_kernel(int* __restrict__ hdr,
                                                    int* __restrict__ rows) {
  if (threadIdx.x == 0) {
    int b = 0;
    for (int e = 0; e < 8; ++e) {
      hdr[16 + e] = b;
      b += ((hdr[e] + 127) >> 7) << 7;
    }
  }
  for (int i = threadIdx.x; i < PAD_ROWS; i += 256) rows[i] = -1;
}

// ---------------------------------------------------------------------------
// K3: scatter token ids into per-expert segments
// ---------------------------------------------------------------------------
__global__ __launch_bounds__(256) void scatter_kernel(const int* __restrict__ idx,
                                                      int* __restrict__ hdr,
                                                      int* __restrict__ rows) {
  int t = blockIdx.x * 256 + threadIdx.x;
  int e = idx[t];
  int p = atomicAdd(&hdr[8 + e], 1);
  rows[hdr[16 + e] + p] = t;
}

// ---------------------------------------------------------------------------
// K4: weight prepass — fp32 W[e][K][N] -> bf16 CHUNK-TILED Wt:
//   Wt[e][kg = k>>3][ng = n>>4][r = n&15][c = k&7], chunk = 16n x 8k = 256B.
// Four wtrans variants all stuck at ~4x BW roofline: a row-major [N][K]
// transpose forces sub-page strided bursts on at least one DRAM side.
// The chunk-tiled layout makes the transpose DRAM-FREE:
//   reads:  per (kk,j) pass, 256 lanes x 4B consecutive n = 1KB contiguous
//           (8-row band; 4 j-passes extend to 4KB per row)
//   writes: lane n packs its own k-column (8 f2bf -> ushort8); consecutive
//           lanes hit consecutive chunk addresses -> 4KB contiguous stores.
// Transpose happens entirely in registers. Grid: (N/1024, K/8, E).
// ---------------------------------------------------------------------------
template <int K, int N>
__global__ __launch_bounds__(256) void cvt_tile_kernel(const float* __restrict__ W,
                                                       unsigned short* __restrict__ Wt) {
  const int e = blockIdx.z;
  const int kg = blockIdx.y;           // 8-row k band
  const int nb = blockIdx.x * 1024;    // n base
  const float* src = W + (size_t)e * K * N + (size_t)kg * 8 * N + nb;
  unsigned short* dst = Wt + (size_t)e * K * N
                        + ((size_t)kg * (N / 16) + (nb >> 4)) * 128;
  const int tid = threadIdx.x;
#pragma unroll
  for (int j = 0; j < 4; ++j) {
    const int n = j * 256 + tid;
    float v[8];
#pragma unroll
    for (int kk = 0; kk < 8; ++kk) v[kk] = src[(size_t)kk * N + n];
    ushort8 o;
#pragma unroll
    for (int kk = 0; kk < 8; ++kk) o[kk] = f2bf(v[kk]);
    *(ushort8*)(dst + (size_t)(n >> 4) * 128 + (n & 15) * 8) = o;
  }
}

// ---------------------------------------------------------------------------
// K5: fused gate+up grouped GEMM. 128x128 tile, BK=64, 256 threads = 4 waves,
// each wave 64x64 via 4x4 frags of mfma_f32_16x16x32_bf16, TWO accumulator
// sets (gate, up). A staged once per k-tile, both B tiles staged -> 32 MFMA
// per barrier pair. Epilogue: inter = silu(g_f32) * u.
// A staging: global_load_lds w16, XOR-swizzled via pre-swizzled SOURCE.
// B staging: chunk-tiled source -> lane-LINEAR 1KB DMA runs (src = base +
// lane*16B); LDS holds [lkg][lng][16n][8k] chunks; B fragment = conflict-free
// ds_read_b128 at (lkg*8+lng)*256B + l15*16B (k-contiguous by construction).
// ---------------------------------------------------------------------------
__global__ __launch_bounds__(256, 2) void moe_gemm_gu(
    const unsigned short* __restrict__ A,
    const unsigned short* __restrict__ Bg,
    const unsigned short* __restrict__ Bu,
    const int* __restrict__ hdr,
    const int* __restrict__ rows,
    unsigned short* __restrict__ inter) {
  const int e = blockIdx.z;
  const int cnt = hdr[e];
  if ((int)blockIdx.y * 128 >= cnt) return;  // uniform early exit
  const int seg = hdr[16 + e];

  const int tid = threadIdx.x;
  const int lane = tid & 63;
  const int wv = tid >> 6;
  const int wm = (wv & 1) * 64;
  const int wn = (wv >> 1) * 64;
  const int q = lane >> 4;
  const int l15 = lane & 15;

  __shared__ unsigned short sA[128 * 64];   // [m][64k], slot-swizzled
  __shared__ unsigned short sBg[64 * 128];  // chunk-tiled [8kg][8ng][16][8]
  __shared__ unsigned short sBu[64 * 128];

  // ---- A staging coords (XOR-swizzled source, linear LDS dest) ----
  const int lr = lane >> 3;            // row within 8-row chunk == row&7
  const int colsw = (lane & 7) ^ lr;   // pre-swizzled 8-elem slot index
  const unsigned short* aptr[4];
#pragma unroll
  for (int j = 0; j < 4; ++j) {
    const int R = j * 32 + wv * 8 + lr;
    int ar = rows[seg + blockIdx.y * 128 + R];
    if (ar < 0) ar = 0;  // padding rows: junk compute, dropped downstream
    aptr[j] = A + (size_t)ar * H_DIM + colsw * 8;
  }

  // ---- B staging coords (chunk-tiled, lane-linear) ----
  const int N16 = I_DIM / 16;  // 256 chunks per kg row
  const int ng0 = blockIdx.x * 8;
  const unsigned short* BgE = Bg + (size_t)e * I_DIM * H_DIM;
  const unsigned short* BuE = Bu + (size_t)e * I_DIM * H_DIM;

  floatx4 accg[4][4], accu[4][4];
#pragma unroll
  for (int a = 0; a < 4; ++a)
#pragma unroll
    for (int b = 0; b < 4; ++b) {
      accg[a][b] = (floatx4){0.f, 0.f, 0.f, 0.f};
      accu[a][b] = (floatx4){0.f, 0.f, 0.f, 0.f};
    }

  // fragment-read lane constants
  const int ubB = q * 1024 + l15 * 8;       // ushort off: quadrant + row
  const int wn16o = (wn >> 4) * 128;        // 0 or 512

  for (int kt = 0; kt < H_DIM; kt += 64) {
    // ---- stage A (swizzled) + B (chunk-linear) via async DMA ----
#pragma unroll
    for (int j = 0; j < 4; ++j) {
      gload_lds16(aptr[j] + kt, sA + (j * 32 + wv * 8) * 64);
      const int g = j * 4 + wv;                        // 0..15 chunk-quad
      const int kgg = (kt >> 3) + (g >> 1);            // global kg
      const size_t so = (size_t)(kgg * N16 + ng0 + (g & 1) * 4) * 128 + lane * 8;
      gload_lds16(BgE + so, sBg + g * 512);
      gload_lds16(BuE + so, sBu + g * 512);
    }
    __syncthreads();  // vmcnt(0): DMA complete for all waves
#pragma unroll
    for (int ks = 0; ks < 64; ks += 32) {
      const int sbase = ks >> 3;       // A swizzle base (8-elem slots)
      const int bbase = ks * 128 + wn16o + ubB;  // B ushort base
      bf16x8 af[4], bfr[4];
#pragma unroll
      for (int fm = 0; fm < 4; ++fm) {
        const int ra = wm + fm * 16 + l15;
        af[fm] = __builtin_bit_cast(bf16x8,
            *(const ushort8*)(sA + ra * 64 + (((q + sbase) ^ (ra & 7)) << 3)));
      }
#pragma unroll
      for (int fn = 0; fn < 4; ++fn)
        bfr[fn] = __builtin_bit_cast(bf16x8,
            *(const ushort8*)(sBg + bbase + fn * 128));
#pragma unroll
      for (int fm = 0; fm < 4; ++fm)
#pragma unroll
        for (int fn = 0; fn < 4; ++fn)
          accg[fm][fn] = __builtin_amdgcn_mfma_f32_16x16x32_bf16(af[fm], bfr[fn],
                                                                 accg[fm][fn], 0, 0, 0);
#pragma unroll
      for (int fn = 0; fn < 4; ++fn)
        bfr[fn] = __builtin_bit_cast(bf16x8,
            *(const ushort8*)(sBu + bbase + fn * 128));
#pragma unroll
      for (int fm = 0; fm < 4; ++fm)
#pragma unroll
        for (int fn = 0; fn < 4; ++fn)
          accu[fm][fn] = __builtin_amdgcn_mfma_f32_16x16x32_bf16(af[fm], bfr[fn],
                                                                 accu[fm][fn], 0, 0, 0);
    }
    __syncthreads();
  }

  // ---- epilogue: C/D layout col=lane&15, row=(lane>>4)*4+reg ----
#pragma unroll
  for (int fm = 0; fm < 4; ++fm)
#pragma unroll
    for (int fn = 0; fn < 4; ++fn)
#pragma unroll
      for (int rr = 0; rr < 4; ++rr) {
        const int row = wm + fm * 16 + q * 4 + rr;
        const int col = wn + fn * 16 + l15;
        const int gm = blockIdx.y * 128 + row;
        const int gn = blockIdx.x * 128 + col;
        const float g = accg[fm][fn][rr];
        const float u = accu[fm][fn][rr];
        const float s = g / (1.f + __expf(-g));  // silu in f32
        inter[(size_t)(seg + gm) * I_DIM + gn] = f2bf(s * u);
      }
}

// ---------------------------------------------------------------------------
// K6: down grouped GEMM, 2-way n-fusion: block computes 128m x 256n (two B
// n-tiles share one staged A) -> 32 MFMA per barrier pair.
// A = inter bf16 [PAD_ROWS][I_DIM] (k-contiguous, segment rows, no gather).
// Bt = chunk-tiled [E][K/8][N/16][16][8] (K=I_DIM, N=H_DIM).
// Scatters fp32 rows to outp by token.
// ---------------------------------------------------------------------------
__global__ __launch_bounds__(256, 2) void moe_gemm_down(
    const unsigned short* __restrict__ A,
    const unsigned short* __restrict__ Bt,
    const int* __restrict__ hdr,
    const int* __restrict__ rows,
    float* __restrict__ outp) {
  const int e = blockIdx.z;
  const int cnt = hdr[e];
  if ((int)blockIdx.y * 128 >= cnt) return;  // uniform early exit
  const int seg = hdr[16 + e];

  const int tid = threadIdx.x;
  const int lane = tid & 63;
  const int wv = tid >> 6;
  const int wm = (wv & 1) * 64;
  const int wn = (wv >> 1) * 64;
  const int q = lane >> 4;
  const int l15 = lane & 15;

  __shared__ unsigned short sA[128 * 64];
  __shared__ unsigned short sB0[64 * 128];
  __shared__ unsigned short sB1[64 * 128];

  const int lr = lane >> 3;
  const int colsw = (lane & 7) ^ lr;
  const unsigned short* aptr[4];
#pragma unroll
  for (int j = 0; j < 4; ++j) {
    const int R = j * 32 + wv * 8 + lr;
    aptr[j] = A + (size_t)(seg + blockIdx.y * 128 + R) * I_DIM + colsw * 8;
  }

  const int N16 = H_DIM / 16;  // 128 chunks per kg row
  const int ng0 = blockIdx.x * 16;
  const unsigned short* Be = Bt + (size_t)e * H_DIM * I_DIM;

  floatx4 acc0[4][4], acc1[4][4];
#pragma unroll
  for (int a = 0; a < 4; ++a)
#pragma unroll
    for (int b = 0; b < 4; ++b) {
      acc0[a][b] = (floatx4){0.f, 0.f, 0.f, 0.f};
      acc1[a][b] = (floatx4){0.f, 0.f, 0.f, 0.f};
    }

  const int ubB = q * 1024 + l15 * 8;
  const int wn16o = (wn >> 4) * 128;

  for (int kt = 0; kt < I_DIM; kt += 64) {
#pragma unroll
    for (int j = 0; j < 4; ++j) {
      gload_lds16(aptr[j] + kt, sA + (j * 32 + wv * 8) * 64);
      const int g = j * 4 + wv;
      const int kgg = (kt >> 3) + (g >> 1);
      const size_t so0 = (size_t)(kgg * N16 + ng0 + (g & 1) * 4) * 128 + lane * 8;
      const size_t so1 = (size_t)(kgg * N16 + ng0 + 8 + (g & 1) * 4) * 128 + lane * 8;
      gload_lds16(Be + so0, sB0 + g * 512);
      gload_lds16(Be + so1, sB1 + g * 512);
    }
    __syncthreads();
#pragma unroll
    for (int ks = 0; ks < 64; ks += 32) {
      const int sbase = ks >> 3;
      const int bbase = ks * 128 + wn16o + ubB;
      bf16x8 af[4], bfr[4];
#pragma unroll
      for (int fm = 0; fm < 4; ++fm) {
        const int ra = wm + fm * 16 + l15;
        af[fm] = __builtin_bit_cast(bf16x8,
            *(const ushort8*)(sA + ra * 64 + (((q + sbase) ^ (ra & 7)) << 3)));
      }
#pragma unroll
      for (int fn = 0; fn < 4; ++fn)
        bfr[fn] = __builtin_bit_cast(bf16x8,
            *(const ushort8*)(sB0 + bbase + fn * 128));
#pragma unroll
      for (int fm = 0; fm < 4; ++fm)
#pragma unroll
        for (int fn = 0; fn < 4; ++fn)
          acc0[fm][fn] = __builtin_amdgcn_mfma_f32_16x16x32_bf16(af[fm], bfr[fn],
                                                                 acc0[fm][fn], 0, 0, 0);
#pragma unroll
      for (int fn = 0; fn < 4; ++fn)
        bfr[fn] = __builtin_bit_cast(bf16x8,
            *(const ushort8*)(sB1 + bbase + fn * 128));
#pragma unroll
      for (int fm = 0; fm < 4; ++fm)
#pragma unroll
        for (int fn = 0; fn < 4; ++fn)
          acc1[fm][fn] = __builtin_amdgcn_mfma_f32_16x16x32_bf16(af[fm], bfr[fn],
                                                                 acc1[fm][fn], 0, 0, 0);
    }
    __syncthreads();
  }

  // ---- epilogue: scatter both n-halves by token ----
#pragma unroll
  for (int fm = 0; fm < 4; ++fm)
#pragma unroll
    for (int rr = 0; rr < 4; ++rr) {
      const int row = wm + fm * 16 + q * 4 + rr;
      const int tok = rows[seg + blockIdx.y * 128 + row];
      if (tok < 0) continue;
      float* orow = outp + (size_t)tok * H_DIM + blockIdx.x * 256;
#pragma unroll
      for (int fn = 0; fn < 4; ++fn) {
        const int col = wn + fn * 16 + l15;
        orow[col]       = acc0[fm][fn][rr];
        orow[128 + col] = acc1[fm][fn][rr];
      }
    }
}

// ---------------------------------------------------------------------------
// host launcher
// ---------------------------------------------------------------------------
extern "C" void kernel_launch(void* const* d_in, const int* in_sizes, int n_in,
                              void* d_out, int out_size, void* d_ws, size_t ws_size,
                              hipStream_t stream) {
  const float* hidden   = (const float*)d_in[0];
  const float* router_w = (const float*)d_in[1];
  const float* gate_w   = (const float*)d_in[2];
  const float* up_w     = (const float*)d_in[3];
  const float* down_w   = (const float*)d_in[4];
  float* out = (float*)d_out;

  char* ws = (char*)d_ws;
  // ws layout (bytes), with time-aliasing (stream-serial kernels):
  //   hdr   @ 0         : 32 ints
  //   idx   @ 1024      : 8192 ints            (32768 B)
  //   rows  @ 33792     : 9216 ints            (36864 B)
  //   x_bf  @ 70656     : 8192*2048 bf16       (33554432 B)
  //   inter @ 33625088  : 9216*4096 bf16       (75497472 B)
  //   W1    @ 109122560 : 134217728 B = gate tiled, then down tiled
  //   W2    @ 243340288 : 134217728 B = up tiled
  //   total = 377558016 B (~378 MB)
  int* hdr  = (int*)ws;
  int* idx  = (int*)(ws + 1024);
  int* rows = (int*)(ws + 33792);
  unsigned short* x_bf  = (unsigned short*)(ws + 70656);
  unsigned short* inter = (unsigned short*)(ws + 33625088);
  unsigned short* W1    = (unsigned short*)(ws + 109122560);
  unsigned short* W2    = (unsigned short*)(ws + 243340288);
  unsigned short* downt = W1;  // alias: gate tiled dead after fused GEMM

  xcvt_kernel<<<T_TOKENS * H_DIM / 1024, 256, 0, stream>>>(hidden, x_bf, hdr);
  router_kernel<<<T_TOKENS / 4, 256, 0, stream>>>(hidden, router_w, idx, hdr);
  setup_kernel<<<1, 256, 0, stream>>>(hdr, rows);
  scatter_kernel<<<T_TOKENS / 256, 256, 0, stream>>>(idx, hdr, rows);

  // weight prepasses (gate, up): fp32 [K][N] -> bf16 chunk-tiled
  cvt_tile_kernel<H_DIM, I_DIM><<<dim3(I_DIM / 1024, H_DIM / 8, E_EXP), 256, 0, stream>>>(gate_w, W1);
  cvt_tile_kernel<H_DIM, I_DIM><<<dim3(I_DIM / 1024, H_DIM / 8, E_EXP), 256, 0, stream>>>(up_w, W2);

  // fused gate+up GEMM: inter = silu(x@gate) * (x@up)
  moe_gemm_gu<<<dim3(I_DIM / 128, 64, E_EXP), 256, 0, stream>>>(
      x_bf, W1, W2, hdr, rows, inter);

  // down prepass into W1 (gate tiled dead), then down GEMM scatters to out
  cvt_tile_kernel<I_DIM, H_DIM><<<dim3(H_DIM / 1024, I_DIM / 8, E_EXP), 256, 0, stream>>>(down_w, downt);
  moe_gemm_down<<<dim3(H_DIM / 256, 64, E_EXP), 256, 0, stream>>>(
      inter, downt, hdr, rows, out);
}